// Round 15
// baseline (1013.455 us; speedup 1.0000x reference)
//
#include <hip/hip_runtime.h>
#include <hip/hip_bf16.h>
#include <math.h>

// B=2048 S=64 D=6 H=4 DM=64 SS=150 A=7 HID=256 FF=256 DH=16
#define NB 2048

#define LD4(p) (*(const float4*)(p))

// out layout (floats): mu[14336] std[14336] seq[19660800] mem[50331648] len[2048]
#define O_STD 14336
#define O_SEQ 28672
#define O_MEM 19689472
#define O_LEN 70021120

// ws layout: xrow fp32 [2048*64] at byte 0 (512KB); bf16 weights at byte 524288.
#define WQT 0
#define WKT 24576
#define WVT 49152
#define WOT 73728
#define W1T 98304
#define W2T 196608
#define WET 294912

typedef __attribute__((ext_vector_type(8))) short short8v;  // 8 bf16 = 4 VGPRs
typedef __attribute__((ext_vector_type(4))) float f32x4;

#define MFMA(a, b, c) __builtin_amdgcn_mfma_f32_16x16x32_bf16((a), (b), (c), 0, 0, 0)

// 0.25 (attn scale) * log2(e): Q pre-scaled so softmax uses exp2 directly.
#define QSC 0.36067376022224087f

// LDS regions (short indices): ACTIVATIONS ONLY (weights read direct from L2).
// L[24576] = 48KB (+fls 2.25KB) -> 3 blocks/CU (12 waves, 3/SIMD).
#define R_SKV   0       // kv_in: mem rows 0-63 @0, h rows 64-127 @4096 -> K (128 rows)
#define R_A1    8192    // O -> T
#define R_VT    12288   // V^T[64][128] 12288..20479
#define R_H2    20480   // Q -> h2

// HW bf16 convert (RNE).
__device__ __forceinline__ short f2bf(float f) {
    return __builtin_bit_cast(short, (__bf16)f);
}
// packed pair convert: one v_cvt_pk_bf16_f32 (lo -> bits 0-15).
__device__ __forceinline__ unsigned pk2(float lo, float hi) {
    union { __hip_bfloat162 h; unsigned u; } t;
    t.h = __float22bfloat162_rn(make_float2(lo, hi));
    return t.u;
}

// ---------------- prep: fp32 weights -> bf16 transposed in ws ----------------
__global__ __launch_bounds__(256) void prep_weights(
        const float* __restrict__ Wq, const float* __restrict__ Wk,
        const float* __restrict__ Wv, const float* __restrict__ Wo,
        const float* __restrict__ W1, const float* __restrict__ W2,
        const float* __restrict__ Wemb, short* __restrict__ wsb) {
    int idx = blockIdx.x * 256 + threadIdx.x;          // grid covers 98304
    {
        int l = idx >> 14, r = idx & 16383;
        { int n = r >> 6, k = r & 63;
          wsb[W1T + idx] = f2bf(W1[l * 16384 + k * 256 + n]); }
        { int n = r >> 8, k = r & 255;
          wsb[W2T + idx] = f2bf(W2[l * 16384 + k * 64 + n]); }
    }
    if (idx < 24576) {                                  // 4 square mats [64n][64k]
        int l = idx >> 12, r = idx & 4095;
        int n = r >> 6, k = r & 63;
        int s = l * 4096 + k * 64 + n;
        wsb[WQT + idx] = f2bf(Wq[s]);
        wsb[WKT + idx] = f2bf(Wk[s]);
        wsb[WVT + idx] = f2bf(Wv[s]);
        wsb[WOT + idx] = f2bf(Wo[s]);
    }
    if (idx < 10240) {                                  // WembT [64n][160k]
        int n = idx / 160, k = idx - n * 160;
        wsb[WET + idx] = (k < 150) ? f2bf(Wemb[k * 64 + n]) : (short)0;
    }
}

// ---------------- small kernels ----------------
__global__ __launch_bounds__(256) void copy4_kernel(const float4* __restrict__ src,
                                                    float4* __restrict__ dst, int n) {
    int i = blockIdx.x * 256 + threadIdx.x;
    if (i < n) dst[i] = src[i];
}

__global__ __launch_bounds__(256) void obs_ln_kernel(const float* __restrict__ obs,
        const float* __restrict__ g, const float* __restrict__ be,
        const int* __restrict__ len, float* __restrict__ outSeq, float* __restrict__ outLen) {
    int w = threadIdx.x >> 6, lane = threadIdx.x & 63;
    int b = blockIdx.x * 4 + w;
    const float* row = obs + (size_t)b * 150;
    float v0 = row[lane], v1 = row[64 + lane];
    float v2 = (lane < 22) ? row[128 + lane] : 0.f;
    float s = v0 + v1 + v2;
    #pragma unroll
    for (int m = 1; m <= 32; m <<= 1) s += __shfl_xor(s, m);
    float mean = s * (1.0f / 150.0f);
    float d0 = v0 - mean, d1 = v1 - mean;
    float d2 = (lane < 22) ? (v2 - mean) : 0.f;
    float q = d0 * d0 + d1 * d1 + d2 * d2;
    #pragma unroll
    for (int m = 1; m <= 32; m <<= 1) q += __shfl_xor(q, m);
    float rs = rsqrtf(q * (1.0f / 150.0f) + 1e-5f);
    int lenraw = len[b];
    int lidx = min(max(lenraw, 0), 63);
    float* orow = outSeq + ((size_t)lidx * NB + b) * 150;
    orow[lane]      = d0 * rs * g[lane] + be[lane];
    orow[64 + lane] = d1 * rs * g[64 + lane] + be[64 + lane];
    if (lane < 22) orow[128 + lane] = d2 * rs * g[128 + lane] + be[128 + lane];
    if (lane == 0) outLen[b] = (float)((lenraw + 1) & 63);
}

// ---------------- MFMA mega kernel: weights direct-from-L2, 4 barriers/layer ----------------
__global__ __launch_bounds__(256, 3) void mega_kernel(
        const float* __restrict__ seq, const float* __restrict__ memory,
        const int* __restrict__ len,
        const float* __restrict__ ln1g, const float* __restrict__ ln1b,
        const float* __restrict__ ln2g, const float* __restrict__ ln2b,
        const float* __restrict__ b1, const float* __restrict__ b2,
        const short* __restrict__ wsb,
        float* __restrict__ memOut, float* __restrict__ xrow) {
    __shared__ short L[24576];
    __shared__ float fls[576];
    float* lnp = fls;
    float* b1f = fls + 256;
    float* b2f = fls + 512;

    const int tid = threadIdx.x;
    const int b = blockIdx.x;
    const int w = tid >> 6;
    const int lane = tid & 63;
    const int g = lane >> 4;
    const int r16 = lane & 15;

    const int lenraw = len[b];
    const int lidx = min(max(lenraw, 0), 63);
    const bool reset = (((lenraw + 1) & 63) == 0);

    // hoisted swizzle constants (LDS activations only; global frags unswizzled)
    const int cxa = (r16 & 7) << 3;
    const int fc0 = (8 * g) ^ cxa;             // LDS frag col, kk=0
    const int fc1 = (32 + 8 * g) ^ cxa;        // LDS frag col, kk=1
    const int gc0 = 8 * g;                     // global frag col, kk=0
    const int gc1 = 32 + 8 * g;                // global frag col, kk=1
    const int cxw = (g & 1) << 5;              // D-write XOR base: cxw|(j<<3)
    const int cxm = ((tid >> 2) & 7) << 3;     // mem-stage row XOR

    const short8v zs = {0, 0, 0, 0, 0, 0, 0, 0};
    const f32x4 zf = {0.f, 0.f, 0.f, 0.f};

    // ---------------- embedding: x = seqB(64x150) @ Wemb ----------------
    #pragma unroll 1
    for (int j = 0; j < 16; ++j) {
        int r = w * 16 + j;
        int rb = r * 160;
        const float* srow = seq + ((size_t)r * NB + b) * 150;
        L[rb + lane]      = f2bf(srow[lane]);
        L[rb + 64 + lane] = f2bf(srow[64 + lane]);
        if (lane < 22)      L[rb + 128 + lane] = f2bf(srow[128 + lane]);
        else if (lane < 32) L[rb + 128 + lane] = 0;
    }
    {
        const int4* s4p = (const int4*)(wsb + WET);
        int4* d4p = (int4*)(L + 10240);
        #pragma unroll
        for (int i = 0; i < 5; ++i) d4p[tid + i * 256] = s4p[tid + i * 256];
    }
    __syncthreads();

    f32x4 x[4] = {zf, zf, zf, zf};
    #pragma unroll
    for (int kk = 0; kk < 5; ++kk) {
        short8v a = *(const short8v*)&L[(16 * w + r16) * 160 + kk * 32 + 8 * g];
        #pragma unroll
        for (int ct = 0; ct < 4; ++ct) {
            short8v bb = *(const short8v*)&L[10240 + (16 * ct + r16) * 160 + kk * 32 + 8 * g];
            x[ct] = MFMA(a, bb, x[ct]);
        }
    }
    __syncthreads();

    // ---------------- 6 transformer layers ----------------
    #pragma unroll 1
    for (int l = 0; l < 6; ++l) {
        const short* wqg = wsb + WQT + l * 4096;
        const short* wkg = wsb + WKT + l * 4096;
        const short* wvg = wsb + WVT + l * 4096;
        const short* wog = wsb + WOT + l * 4096;
        const short* w1g = wsb + W1T + l * 16384;
        const short* w2g = wsb + W2T + l * 16384;

        // ---- phase 0: lnp/biases + mem -> SKV rows 0..63 + memOut ----
        if (tid < 64) {
            lnp[tid]       = ln1g[l * 64 + tid];
            lnp[64 + tid]  = ln1b[l * 64 + tid];
            lnp[128 + tid] = ln2g[l * 64 + tid];
            lnp[192 + tid] = ln2b[l * 64 + tid];
            b2f[tid]       = b2[l * 64 + tid];
        }
        b1f[tid] = b1[l * 256 + tid];
        {
            const float* gmem = memory + ((size_t)l * NB + b) * 4096;
            float* gout = memOut + ((size_t)l * NB + b) * 4096;
            int rr = tid >> 2, c0 = (tid & 3) * 16;
            #pragma unroll
            for (int k4 = 0; k4 < 4; ++k4) {
                float4 v = LD4(&gmem[rr * 64 + c0 + k4 * 4]);
                if (!reset) *(float4*)&gout[rr * 64 + c0 + k4 * 4] = v;
                uint2 su;
                su.x = pk2(v.x, v.y); su.y = pk2(v.z, v.w);
                *(uint2*)&L[rr * 64 + ((c0 + k4 * 4) ^ cxm)] = su;
            }
            if (reset) {
                #pragma unroll
                for (int ct = 0; ct < 4; ++ct)
                    #pragma unroll
                    for (int j = 0; j < 4; ++j)
                        gout[(16 * w + 4 * g + j) * 64 + 16 * ct + r16] = x[ct][j];
            }
        }
        __syncthreads();   // S1a: lnp + mem tile visible

        // ---- LN1(x) -> SKV rows 64..127 (own-wave stripes; no barrier) ----
        #pragma unroll
        for (int j = 0; j < 4; ++j) {
            float s = x[0][j] + x[1][j] + x[2][j] + x[3][j];
            s += __shfl_xor(s, 1); s += __shfl_xor(s, 2);
            s += __shfl_xor(s, 4); s += __shfl_xor(s, 8);
            float m = s * 0.015625f;
            float q = 0.f;
            #pragma unroll
            for (int ct = 0; ct < 4; ++ct) { float d = x[ct][j] - m; q += d * d; }
            q += __shfl_xor(q, 1); q += __shfl_xor(q, 2);
            q += __shfl_xor(q, 4); q += __shfl_xor(q, 8);
            float rs = rsqrtf(q * 0.015625f + 1e-5f);
            #pragma unroll
            for (int ct = 0; ct < 4; ++ct) {
                int col = 16 * ct + r16;
                float hv = (x[ct][j] - m) * rs * lnp[col] + lnp[64 + col];
                L[(64 + 16 * w + 4 * g + j) * 64 + (col ^ (cxw | (j << 3)))] = f2bf(hv);
            }
        }

        // ---- Q + K GEMMs (pass 1): A from LDS own stripes, B from global (L2) ----
        f32x4 qa[4] = {zf, zf, zf, zf};
        f32x4 ka[2][4] = {{zf, zf, zf, zf}, {zf, zf, zf, zf}};
        #pragma unroll
        for (int kk = 0; kk < 2; ++kk) {
            const int fc = kk ? fc1 : fc0;
            const int gcol = kk ? gc1 : gc0;
            short8v ah = *(const short8v*)&L[(64 + 16 * w + r16) * 64 + fc];
            short8v a0 = *(const short8v*)&L[(16 * w + r16) * 64 + fc];
            #pragma unroll
            for (int ct = 0; ct < 4; ++ct) {
                const int ro = (16 * ct + r16) * 64 + gcol;
                short8v bq = *(const short8v*)&wqg[ro];
                short8v bk = *(const short8v*)&wkg[ro];
                qa[ct]    = MFMA(ah, bq, qa[ct]);
                ka[0][ct] = MFMA(a0, bk, ka[0][ct]);
                ka[1][ct] = MFMA(ah, bk, ka[1][ct]);
            }
        }
        // pack Q -> R_H2 (own stripes; prev h2 dead; visibility via S3)
        #pragma unroll
        for (int ct = 0; ct < 4; ++ct)
            #pragma unroll
            for (int j = 0; j < 4; ++j)
                L[R_H2 + (16 * w + 4 * g + j) * 64 + ((16 * ct + r16) ^ (cxw | (j << 3)))] =
                    f2bf(qa[ct][j] * QSC);

        // ---- V GEMM (pass 2) ----
        f32x4 va[2][4] = {{zf, zf, zf, zf}, {zf, zf, zf, zf}};
        #pragma unroll
        for (int kk = 0; kk < 2; ++kk) {
            const int fc = kk ? fc1 : fc0;
            const int gcol = kk ? gc1 : gc0;
            short8v ah = *(const short8v*)&L[(64 + 16 * w + r16) * 64 + fc];
            short8v a0 = *(const short8v*)&L[(16 * w + r16) * 64 + fc];
            #pragma unroll
            for (int ct = 0; ct < 4; ++ct) {
                short8v bv = *(const short8v*)&wvg[(16 * ct + r16) * 64 + gcol];
                va[0][ct] = MFMA(a0, bv, va[0][ct]);
                va[1][ct] = MFMA(ah, bv, va[1][ct]);
            }
        }

        // pack K -> SKV (own stripes over kv_in) and V -> R_VT as permuted V^T
        #pragma unroll
        for (int ct = 0; ct < 4; ++ct) {
            #pragma unroll
            for (int j = 0; j < 4; ++j) {
                int key0 = 16 * w + 4 * g + j;
                int colw = (16 * ct + r16) ^ (cxw | (j << 3));
                L[key0 * 64 + colw] = f2bf(ka[0][ct][j]);
                L[(64 + key0) * 64 + colw] = f2bf(ka[1][ct][j]);
            }
        }
        {
            const int p0 = ((w >> 1) << 5) | (g << 3) | ((w & 1) << 2);  // perm(key0)
            const int p1 = p0 | 64;                                       // perm(key0+64)
            #pragma unroll
            for (int ct = 0; ct < 4; ++ct) {
                int rowb = R_VT + (16 * ct + r16) * 128;
                uint2 v0, v1;
                v0.x = pk2(va[0][ct][0], va[0][ct][1]);
                v0.y = pk2(va[0][ct][2], va[0][ct][3]);
                v1.x = pk2(va[1][ct][0], va[1][ct][1]);
                v1.y = pk2(va[1][ct][2], va[1][ct][3]);
                *(uint2*)&L[rowb + (p0 ^ cxa)] = v0;
                *(uint2*)&L[rowb + (p1 ^ cxa)] = v1;
            }
        }
        __syncthreads();   // S3: K/V^T/Q packs visible

        // ---- attention: wave w = head; causal-skipped blocks, no-max exp2 softmax ----
        const int hc = 16 * w;
        const int attc = (hc + 8 * g) ^ cxa;
        const int obc  = (hc + 4 * g) ^ cxa;
        #pragma unroll
        for (int qt = 0; qt < 4; ++qt) {
            const int KT = 5 + qt;
            short8v bQ = (g < 2) ? *(const short8v*)&L[R_H2 + (16 * qt + r16) * 64 + attc] : zs;
            f32x4 s[8];
            #pragma unroll
            for (int kt = 0; kt < 8; ++kt) if (kt < KT) {
                short8v aK = *(const short8v*)&L[(16 * kt + r16) * 64 + attc];
                s[kt] = MFMA(aK, bQ, zf);
            }
            float sum = 0.f;
            #pragma unroll
            for (int kt = 0; kt < 8; ++kt) if (kt < KT) {
                #pragma unroll
                for (int j = 0; j < 4; ++j) {
                    float e = exp2f(s[kt][j]);
                    if (kt == KT - 1) e = ((4 * g + j) > r16) ? 0.f : e;
                    s[kt][j] = e; sum += e;
                }
            }
            sum += __shfl_xor(sum, 16);
            sum += __shfl_xor(sum, 32);
            float inv = 1.0f / sum;
            f32x4 of = zf;
            const int KT2 = (KT + 1) >> 1;
            #pragma unroll
            for (int kt2 = 0; kt2 < 4; ++kt2) if (kt2 < KT2) {
                short8v aV = *(const short8v*)&L[R_VT + (hc + r16) * 128 +
                                                 ((32 * kt2 + 8 * g) ^ cxa)];
                union { short8v v; unsigned u[4]; } pb;
                const int i0 = 2 * kt2, i1 = 2 * kt2 + 1;
                pb.u[0] = pk2(s[i0][0], s[i0][1]);
                pb.u[1] = pk2(s[i0][2], s[i0][3]);
                pb.u[2] = (i1 < KT) ? pk2(s[i1][0], s[i1][1]) : 0u;
                pb.u[3] = (i1 < KT) ? pk2(s[i1][2], s[i1][3]) : 0u;
                of = MFMA(aV, pb.v, of);
            }
            uint2 ov;
            ov.x = pk2(of[0] * inv, of[1] * inv);
            ov.y = pk2(of[2] * inv, of[3] * inv);
            *(uint2*)&L[R_A1 + (16 * qt + r16) * 64 + obc] = ov;
        }
        __syncthreads();   // S4: attention reads done; O visible

        // ---- x += O @ Wo (B direct from global) ----
        #pragma unroll
        for (int kk = 0; kk < 2; ++kk) {
            const int fc = kk ? fc1 : fc0;
            const int gcol = kk ? gc1 : gc0;
            short8v a = *(const short8v*)&L[R_A1 + (16 * w + r16) * 64 + fc];
            #pragma unroll
            for (int ct = 0; ct < 4; ++ct) {
                short8v bb = *(const short8v*)&wog[(16 * ct + r16) * 64 + gcol];
                x[ct] = MFMA(a, bb, x[ct]);
            }
        }
        // ---- LN2(x) -> R_H2 (Q dead after S4; own stripes; no barrier) ----
        #pragma unroll
        for (int j = 0; j < 4; ++j) {
            float s = x[0][j] + x[1][j] + x[2][j] + x[3][j];
            s += __shfl_xor(s, 1); s += __shfl_xor(s, 2);
            s += __shfl_xor(s, 4); s += __shfl_xor(s, 8);
            float m = s * 0.015625f;
            float q = 0.f;
            #pragma unroll
            for (int ct = 0; ct < 4; ++ct) { float d = x[ct][j] - m; q += d * d; }
            q += __shfl_xor(q, 1); q += __shfl_xor(q, 2);
            q += __shfl_xor(q, 4); q += __shfl_xor(q, 8);
            float rs = rsqrtf(q * 0.015625f + 1e-5f);
            #pragma unroll
            for (int ct = 0; ct < 4; ++ct) {
                int col = 16 * ct + r16;
                float hv = (x[ct][j] - m) * rs * lnp[128 + col] + lnp[192 + col];
                L[R_H2 + (16 * w + 4 * g + j) * 64 + (col ^ (cxw | (j << 3)))] = f2bf(hv);
            }
        }

        // ---- FF: x += relu(h2@W1+b1)@W2 + b2 — ZERO barriers (weights from L2,
        //      h2/T are own-wave stripes) ----
        #pragma unroll
        for (int kb = 0; kb < 4; ++kb) {
            f32x4 tacc[4] = {zf, zf, zf, zf};
            #pragma unroll
            for (int kk = 0; kk < 2; ++kk) {
                const int fc = kk ? fc1 : fc0;
                const int gcol = kk ? gc1 : gc0;
                short8v a = *(const short8v*)&L[R_H2 + (16 * w + r16) * 64 + fc];
                #pragma unroll
                for (int ct = 0; ct < 4; ++ct) {
                    short8v bb = *(const short8v*)&w1g[(kb * 64 + 16 * ct + r16) * 64 + gcol];
                    tacc[ct] = MFMA(a, bb, tacc[ct]);
                }
            }
            #pragma unroll
            for (int ct = 0; ct < 4; ++ct)
                #pragma unroll
                for (int j = 0; j < 4; ++j) {
                    float v = fmaxf(tacc[ct][j] + b1f[kb * 64 + 16 * ct + r16], 0.f);
                    L[R_A1 + (16 * w + 4 * g + j) * 64 + ((16 * ct + r16) ^ (cxw | (j << 3)))] = f2bf(v);
                }
            #pragma unroll
            for (int kk = 0; kk < 2; ++kk) {
                const int fc = kk ? fc1 : fc0;
                const int gcol = kk ? gc1 : gc0;
                short8v a = *(const short8v*)&L[R_A1 + (16 * w + r16) * 64 + fc];
                #pragma unroll
                for (int ct = 0; ct < 4; ++ct) {
                    short8v bb = *(const short8v*)&w2g[(16 * ct + r16) * 256 + kb * 64 + gcol];
                    x[ct] = MFMA(a, bb, x[ct]);
                }
            }
        }
        #pragma unroll
        for (int ct = 0; ct < 4; ++ct)
            #pragma unroll
            for (int j = 0; j < 4; ++j) x[ct][j] += b2f[16 * ct + r16];
        __syncthreads();   // S9L: fls/b1f reads done -> next layer phase-0 safe
    }

    // ---- output row x[lidx] -> xrow ----
    if (w == (lidx >> 4) && g == ((lidx >> 2) & 3)) {
        int j = lidx & 3;
        #pragma unroll
        for (int ct = 0; ct < 4; ++ct) {
            float v = (j == 0) ? x[ct][0] : (j == 1) ? x[ct][1] : (j == 2) ? x[ct][2] : x[ct][3];
            xrow[(size_t)b * 64 + 16 * ct + r16] = v;
        }
    }
}

__device__ __forceinline__ float softplusf(float v) {
    return fmaxf(v, 0.f) + log1pf(expf(-fabsf(v)));
}

__global__ __launch_bounds__(256) void policy_kernel(const float* __restrict__ xrow,
        const float* __restrict__ Wp1, const float* __restrict__ bp1,
        const float* __restrict__ Wp2, const float* __restrict__ bp2,
        float* __restrict__ outMu, float* __restrict__ outStd) {
    __shared__ float sx[64];
    __shared__ float sh1[256];
    const int tid = threadIdx.x;
    for (int bi = 0; bi < 16; ++bi) {
        int b = blockIdx.x * 16 + bi;
        if (tid < 64) sx[tid] = xrow[(size_t)b * 64 + tid];
        __syncthreads();
        float acc = bp1[tid];
        #pragma unroll 16
        for (int k = 0; k < 64; ++k) acc = fmaf(sx[k], Wp1[k * 256 + tid], acc);
        sh1[tid] = fmaxf(acc, 0.f);
        __syncthreads();
        if (tid < 224) {
            int j = tid >> 4, gg = tid & 15;
            float a = 0.f;
            #pragma unroll
            for (int kk = 0; kk < 16; ++kk) {
                int k = gg * 16 + kk;
                a = fmaf(sh1[k], Wp2[k * 14 + j], a);
            }
            a += __shfl_xor(a, 1); a += __shfl_xor(a, 2);
            a += __shfl_xor(a, 4); a += __shfl_xor(a, 8);
            if (gg == 0) {
                float pol = a + bp2[j];
                if (j < 7) outStd[(size_t)b * 7 + j] = softplusf(pol);
                else       outMu[(size_t)b * 7 + (j - 7)] = tanhf(pol);
            }
        }
        __syncthreads();
    }
}

extern "C" void kernel_launch(void* const* d_in, const int* in_sizes, int n_in,
                              void* d_out, int out_size, void* d_ws, size_t ws_size,
                              hipStream_t stream) {
    const float* obs   = (const float*)d_in[0];
    const float* seqIn = (const float*)d_in[1];
    const float* mem   = (const float*)d_in[2];
    const int*   len   = (const int*)d_in[3];
    const float* ln_g  = (const float*)d_in[4];
    const float* ln_b  = (const float*)d_in[5];
    const float* Wemb  = (const float*)d_in[6];
    const float* ln1g  = (const float*)d_in[7];
    const float* ln1b  = (const float*)d_in[8];
    const float* ln2g  = (const float*)d_in[9];
    const float* ln2b  = (const float*)d_in[10];
    const float* Wq    = (const float*)d_in[11];
    const float* Wk    = (const float*)d_in[12];
    const float* Wv    = (const float*)d_in[13];
    const float* Wo    = (const float*)d_in[14];
    const float* W1    = (const float*)d_in[15];
    const float* b1    = (const float*)d_in[16];
    const float* W2    = (const float*)d_in[17];
    const float* b2    = (const float*)d_in[18];
    const float* Wp1   = (const float*)d_in[19];
    const float* bp1   = (const float*)d_in[20];
    const float* Wp2   = (const float*)d_in[21];
    const float* bp2   = (const float*)d_in[22];

    float* out    = (float*)d_out;
    float* outMu  = out;
    float* outStd = out + O_STD;
    float* outSeq = out + O_SEQ;
    float* outMem = out + O_MEM;
    float* outLen = out + O_LEN;
    float* xrow   = (float*)d_ws;
    short* wsb    = (short*)((char*)d_ws + 524288);

    hipLaunchKernelGGL(prep_weights, dim3(384), dim3(256), 0, stream,
                       Wq, Wk, Wv, Wo, W1, W2, Wemb, wsb);
    hipLaunchKernelGGL(copy4_kernel, dim3(19200), dim3(256), 0, stream,
                       (const float4*)seqIn, (float4*)outSeq, 4915200);
    hipLaunchKernelGGL(obs_ln_kernel, dim3(512), dim3(256), 0, stream,
                       obs, ln_g, ln_b, len, outSeq, outLen);
    hipLaunchKernelGGL(mega_kernel, dim3(2048), dim3(256), 0, stream,
                       outSeq, mem, len, ln1g, ln1b, ln2g, ln2b, b1, b2,
                       wsb, outMem, xrow);
    hipLaunchKernelGGL(policy_kernel, dim3(128), dim3(256), 0, stream,
                       xrow, Wp1, bp1, Wp2, bp2, outMu, outStd);
}

// Round 16
// 798.824 us; speedup vs baseline: 1.2687x; 1.2687x over previous
//
#include <hip/hip_runtime.h>
#include <hip/hip_bf16.h>
#include <math.h>

// B=2048 S=64 D=6 H=4 DM=64 SS=150 A=7 HID=256 FF=256 DH=16
#define NB 2048

#define LD4(p) (*(const float4*)(p))

// out layout (floats): mu[14336] std[14336] seq[19660800] mem[50331648] len[2048]
#define O_STD 14336
#define O_SEQ 28672
#define O_MEM 19689472
#define O_LEN 70021120

// ws layout: xrow fp32 [2048*64] at byte 0 (512KB); bf16 weights at byte 524288.
#define WQT 0
#define WKT 24576
#define WVT 49152
#define WOT 73728
#define W1T 98304
#define W2T 196608
#define WET 294912

typedef __attribute__((ext_vector_type(8))) short short8v;  // 8 bf16 = 4 VGPRs
typedef __attribute__((ext_vector_type(4))) float f32x4;

#define MFMA(a, b, c) __builtin_amdgcn_mfma_f32_16x16x32_bf16((a), (b), (c), 0, 0, 0)

// 0.25 (attn scale) * log2(e): Q pre-scaled so softmax uses exp2 directly.
#define QSC 0.36067376022224087f

// LDS regions (short indices): ACTIVATIONS ONLY (weights read direct from L2).
// L[24576] = 48KB (+fls 2.25KB) -> 3 blocks/CU (12 waves, 3/SIMD).
#define R_SKV   0       // kv_in: mem rows 0-63 @0, h rows 64-127 @4096 -> K (128 rows)
#define R_A1    8192    // O -> T
#define R_VT    12288   // V^T[64][128] 12288..20479
#define R_H2    20480   // Q -> h2

// HW bf16 convert (RNE).
__device__ __forceinline__ short f2bf(float f) {
    return __builtin_bit_cast(short, (__bf16)f);
}
// packed pair convert: one v_cvt_pk_bf16_f32 (lo -> bits 0-15).
__device__ __forceinline__ unsigned pk2(float lo, float hi) {
    union { __hip_bfloat162 h; unsigned u; } t;
    t.h = __float22bfloat162_rn(make_float2(lo, hi));
    return t.u;
}

// ---------------- prep: fp32 weights -> bf16 transposed in ws ----------------
__global__ __launch_bounds__(256) void prep_weights(
        const float* __restrict__ Wq, const float* __restrict__ Wk,
        const float* __restrict__ Wv, const float* __restrict__ Wo,
        const float* __restrict__ W1, const float* __restrict__ W2,
        const float* __restrict__ Wemb, short* __restrict__ wsb) {
    int idx = blockIdx.x * 256 + threadIdx.x;          // grid covers 98304
    {
        int l = idx >> 14, r = idx & 16383;
        { int n = r >> 6, k = r & 63;
          wsb[W1T + idx] = f2bf(W1[l * 16384 + k * 256 + n]); }
        { int n = r >> 8, k = r & 255;
          wsb[W2T + idx] = f2bf(W2[l * 16384 + k * 64 + n]); }
    }
    if (idx < 24576) {                                  // 4 square mats [64n][64k]
        int l = idx >> 12, r = idx & 4095;
        int n = r >> 6, k = r & 63;
        int s = l * 4096 + k * 64 + n;
        wsb[WQT + idx] = f2bf(Wq[s]);
        wsb[WKT + idx] = f2bf(Wk[s]);
        wsb[WVT + idx] = f2bf(Wv[s]);
        wsb[WOT + idx] = f2bf(Wo[s]);
    }
    if (idx < 10240) {                                  // WembT [64n][160k]
        int n = idx / 160, k = idx - n * 160;
        wsb[WET + idx] = (k < 150) ? f2bf(Wemb[k * 64 + n]) : (short)0;
    }
}

// ---------------- small kernels ----------------
__global__ __launch_bounds__(256) void copy4_kernel(const float4* __restrict__ src,
                                                    float4* __restrict__ dst, int n) {
    int i = blockIdx.x * 256 + threadIdx.x;
    if (i < n) dst[i] = src[i];
}

__global__ __launch_bounds__(256) void obs_ln_kernel(const float* __restrict__ obs,
        const float* __restrict__ g, const float* __restrict__ be,
        const int* __restrict__ len, float* __restrict__ outSeq, float* __restrict__ outLen) {
    int w = threadIdx.x >> 6, lane = threadIdx.x & 63;
    int b = blockIdx.x * 4 + w;
    const float* row = obs + (size_t)b * 150;
    float v0 = row[lane], v1 = row[64 + lane];
    float v2 = (lane < 22) ? row[128 + lane] : 0.f;
    float s = v0 + v1 + v2;
    #pragma unroll
    for (int m = 1; m <= 32; m <<= 1) s += __shfl_xor(s, m);
    float mean = s * (1.0f / 150.0f);
    float d0 = v0 - mean, d1 = v1 - mean;
    float d2 = (lane < 22) ? (v2 - mean) : 0.f;
    float q = d0 * d0 + d1 * d1 + d2 * d2;
    #pragma unroll
    for (int m = 1; m <= 32; m <<= 1) q += __shfl_xor(q, m);
    float rs = rsqrtf(q * (1.0f / 150.0f) + 1e-5f);
    int lenraw = len[b];
    int lidx = min(max(lenraw, 0), 63);
    float* orow = outSeq + ((size_t)lidx * NB + b) * 150;
    orow[lane]      = d0 * rs * g[lane] + be[lane];
    orow[64 + lane] = d1 * rs * g[64 + lane] + be[64 + lane];
    if (lane < 22) orow[128 + lane] = d2 * rs * g[128 + lane] + be[128 + lane];
    if (lane == 0) outLen[b] = (float)((lenraw + 1) & 63);
}

// ---------------- MFMA mega kernel: weights direct-from-L2, 4 barriers/layer ----------------
// launch_bounds (256, 2): r15's (256,3) made the allocator target the 6-wave
// VGPR class (84) and spill ~1.1GB of scratch (same failure as r11's (512,4)).
// Min-2 bound -> 256-VGPR cap -> allocator settles ~124 with no spill; LDS
// (50.5KB) still admits 3 blocks/CU.
__global__ __launch_bounds__(256, 2) void mega_kernel(
        const float* __restrict__ seq, const float* __restrict__ memory,
        const int* __restrict__ len,
        const float* __restrict__ ln1g, const float* __restrict__ ln1b,
        const float* __restrict__ ln2g, const float* __restrict__ ln2b,
        const float* __restrict__ b1, const float* __restrict__ b2,
        const short* __restrict__ wsb,
        float* __restrict__ memOut, float* __restrict__ xrow) {
    __shared__ short L[24576];
    __shared__ float fls[576];
    float* lnp = fls;
    float* b1f = fls + 256;
    float* b2f = fls + 512;

    const int tid = threadIdx.x;
    const int b = blockIdx.x;
    const int w = tid >> 6;
    const int lane = tid & 63;
    const int g = lane >> 4;
    const int r16 = lane & 15;

    const int lenraw = len[b];
    const int lidx = min(max(lenraw, 0), 63);
    const bool reset = (((lenraw + 1) & 63) == 0);

    // hoisted swizzle constants (LDS activations only; global frags unswizzled)
    const int cxa = (r16 & 7) << 3;
    const int fc0 = (8 * g) ^ cxa;             // LDS frag col, kk=0
    const int fc1 = (32 + 8 * g) ^ cxa;        // LDS frag col, kk=1
    const int gc0 = 8 * g;                     // global frag col, kk=0
    const int gc1 = 32 + 8 * g;                // global frag col, kk=1
    const int cxw = (g & 1) << 5;              // D-write XOR base: cxw|(j<<3)
    const int cxm = ((tid >> 2) & 7) << 3;     // mem-stage row XOR

    const short8v zs = {0, 0, 0, 0, 0, 0, 0, 0};
    const f32x4 zf = {0.f, 0.f, 0.f, 0.f};

    // ---------------- embedding: x = seqB(64x150) @ Wemb ----------------
    #pragma unroll 1
    for (int j = 0; j < 16; ++j) {
        int r = w * 16 + j;
        int rb = r * 160;
        const float* srow = seq + ((size_t)r * NB + b) * 150;
        L[rb + lane]      = f2bf(srow[lane]);
        L[rb + 64 + lane] = f2bf(srow[64 + lane]);
        if (lane < 22)      L[rb + 128 + lane] = f2bf(srow[128 + lane]);
        else if (lane < 32) L[rb + 128 + lane] = 0;
    }
    {
        const int4* s4p = (const int4*)(wsb + WET);
        int4* d4p = (int4*)(L + 10240);
        #pragma unroll
        for (int i = 0; i < 5; ++i) d4p[tid + i * 256] = s4p[tid + i * 256];
    }
    __syncthreads();

    f32x4 x[4] = {zf, zf, zf, zf};
    #pragma unroll
    for (int kk = 0; kk < 5; ++kk) {
        short8v a = *(const short8v*)&L[(16 * w + r16) * 160 + kk * 32 + 8 * g];
        #pragma unroll
        for (int ct = 0; ct < 4; ++ct) {
            short8v bb = *(const short8v*)&L[10240 + (16 * ct + r16) * 160 + kk * 32 + 8 * g];
            x[ct] = MFMA(a, bb, x[ct]);
        }
    }
    __syncthreads();

    // ---------------- 6 transformer layers ----------------
    #pragma unroll 1
    for (int l = 0; l < 6; ++l) {
        const short* wqg = wsb + WQT + l * 4096;
        const short* wkg = wsb + WKT + l * 4096;
        const short* wvg = wsb + WVT + l * 4096;
        const short* wog = wsb + WOT + l * 4096;
        const short* w1g = wsb + W1T + l * 16384;
        const short* w2g = wsb + W2T + l * 16384;

        // ---- phase 0: lnp/biases + mem -> SKV rows 0..63 + memOut ----
        if (tid < 64) {
            lnp[tid]       = ln1g[l * 64 + tid];
            lnp[64 + tid]  = ln1b[l * 64 + tid];
            lnp[128 + tid] = ln2g[l * 64 + tid];
            lnp[192 + tid] = ln2b[l * 64 + tid];
            b2f[tid]       = b2[l * 64 + tid];
        }
        b1f[tid] = b1[l * 256 + tid];
        {
            const float* gmem = memory + ((size_t)l * NB + b) * 4096;
            float* gout = memOut + ((size_t)l * NB + b) * 4096;
            int rr = tid >> 2, c0 = (tid & 3) * 16;
            #pragma unroll
            for (int k4 = 0; k4 < 4; ++k4) {
                float4 v = LD4(&gmem[rr * 64 + c0 + k4 * 4]);
                if (!reset) *(float4*)&gout[rr * 64 + c0 + k4 * 4] = v;
                uint2 su;
                su.x = pk2(v.x, v.y); su.y = pk2(v.z, v.w);
                *(uint2*)&L[rr * 64 + ((c0 + k4 * 4) ^ cxm)] = su;
            }
            if (reset) {
                #pragma unroll
                for (int ct = 0; ct < 4; ++ct)
                    #pragma unroll
                    for (int j = 0; j < 4; ++j)
                        gout[(16 * w + 4 * g + j) * 64 + 16 * ct + r16] = x[ct][j];
            }
        }
        __syncthreads();   // S1a: lnp + mem tile visible

        // ---- LN1(x) -> SKV rows 64..127 (own-wave stripes; no barrier) ----
        #pragma unroll
        for (int j = 0; j < 4; ++j) {
            float s = x[0][j] + x[1][j] + x[2][j] + x[3][j];
            s += __shfl_xor(s, 1); s += __shfl_xor(s, 2);
            s += __shfl_xor(s, 4); s += __shfl_xor(s, 8);
            float m = s * 0.015625f;
            float q = 0.f;
            #pragma unroll
            for (int ct = 0; ct < 4; ++ct) { float d = x[ct][j] - m; q += d * d; }
            q += __shfl_xor(q, 1); q += __shfl_xor(q, 2);
            q += __shfl_xor(q, 4); q += __shfl_xor(q, 8);
            float rs = rsqrtf(q * 0.015625f + 1e-5f);
            #pragma unroll
            for (int ct = 0; ct < 4; ++ct) {
                int col = 16 * ct + r16;
                float hv = (x[ct][j] - m) * rs * lnp[col] + lnp[64 + col];
                L[(64 + 16 * w + 4 * g + j) * 64 + (col ^ (cxw | (j << 3)))] = f2bf(hv);
            }
        }

        // ---- Q + K GEMMs (pass 1): A from LDS own stripes, B from global (L2) ----
        f32x4 qa[4] = {zf, zf, zf, zf};
        f32x4 ka[2][4] = {{zf, zf, zf, zf}, {zf, zf, zf, zf}};
        #pragma unroll
        for (int kk = 0; kk < 2; ++kk) {
            const int fc = kk ? fc1 : fc0;
            const int gcol = kk ? gc1 : gc0;
            short8v ah = *(const short8v*)&L[(64 + 16 * w + r16) * 64 + fc];
            short8v a0 = *(const short8v*)&L[(16 * w + r16) * 64 + fc];
            #pragma unroll
            for (int ct = 0; ct < 4; ++ct) {
                const int ro = (16 * ct + r16) * 64 + gcol;
                short8v bq = *(const short8v*)&wqg[ro];
                short8v bk = *(const short8v*)&wkg[ro];
                qa[ct]    = MFMA(ah, bq, qa[ct]);
                ka[0][ct] = MFMA(a0, bk, ka[0][ct]);
                ka[1][ct] = MFMA(ah, bk, ka[1][ct]);
            }
        }
        // pack Q -> R_H2 (own stripes; prev h2 dead; visibility via S3)
        #pragma unroll
        for (int ct = 0; ct < 4; ++ct)
            #pragma unroll
            for (int j = 0; j < 4; ++j)
                L[R_H2 + (16 * w + 4 * g + j) * 64 + ((16 * ct + r16) ^ (cxw | (j << 3)))] =
                    f2bf(qa[ct][j] * QSC);

        // ---- V GEMM (pass 2) ----
        f32x4 va[2][4] = {{zf, zf, zf, zf}, {zf, zf, zf, zf}};
        #pragma unroll
        for (int kk = 0; kk < 2; ++kk) {
            const int fc = kk ? fc1 : fc0;
            const int gcol = kk ? gc1 : gc0;
            short8v ah = *(const short8v*)&L[(64 + 16 * w + r16) * 64 + fc];
            short8v a0 = *(const short8v*)&L[(16 * w + r16) * 64 + fc];
            #pragma unroll
            for (int ct = 0; ct < 4; ++ct) {
                short8v bv = *(const short8v*)&wvg[(16 * ct + r16) * 64 + gcol];
                va[0][ct] = MFMA(a0, bv, va[0][ct]);
                va[1][ct] = MFMA(ah, bv, va[1][ct]);
            }
        }

        // pack K -> SKV (own stripes over kv_in) and V -> R_VT as permuted V^T
        #pragma unroll
        for (int ct = 0; ct < 4; ++ct) {
            #pragma unroll
            for (int j = 0; j < 4; ++j) {
                int key0 = 16 * w + 4 * g + j;
                int colw = (16 * ct + r16) ^ (cxw | (j << 3));
                L[key0 * 64 + colw] = f2bf(ka[0][ct][j]);
                L[(64 + key0) * 64 + colw] = f2bf(ka[1][ct][j]);
            }
        }
        {
            const int p0 = ((w >> 1) << 5) | (g << 3) | ((w & 1) << 2);  // perm(key0)
            const int p1 = p0 | 64;                                       // perm(key0+64)
            #pragma unroll
            for (int ct = 0; ct < 4; ++ct) {
                int rowb = R_VT + (16 * ct + r16) * 128;
                uint2 v0, v1;
                v0.x = pk2(va[0][ct][0], va[0][ct][1]);
                v0.y = pk2(va[0][ct][2], va[0][ct][3]);
                v1.x = pk2(va[1][ct][0], va[1][ct][1]);
                v1.y = pk2(va[1][ct][2], va[1][ct][3]);
                *(uint2*)&L[rowb + (p0 ^ cxa)] = v0;
                *(uint2*)&L[rowb + (p1 ^ cxa)] = v1;
            }
        }
        __syncthreads();   // S3: K/V^T/Q packs visible

        // ---- attention: wave w = head; causal-skipped blocks, no-max exp2 softmax ----
        const int hc = 16 * w;
        const int attc = (hc + 8 * g) ^ cxa;
        const int obc  = (hc + 4 * g) ^ cxa;
        #pragma unroll
        for (int qt = 0; qt < 4; ++qt) {
            const int KT = 5 + qt;
            short8v bQ = (g < 2) ? *(const short8v*)&L[R_H2 + (16 * qt + r16) * 64 + attc] : zs;
            f32x4 s[8];
            #pragma unroll
            for (int kt = 0; kt < 8; ++kt) if (kt < KT) {
                short8v aK = *(const short8v*)&L[(16 * kt + r16) * 64 + attc];
                s[kt] = MFMA(aK, bQ, zf);
            }
            float sum = 0.f;
            #pragma unroll
            for (int kt = 0; kt < 8; ++kt) if (kt < KT) {
                #pragma unroll
                for (int j = 0; j < 4; ++j) {
                    float e = exp2f(s[kt][j]);
                    if (kt == KT - 1) e = ((4 * g + j) > r16) ? 0.f : e;
                    s[kt][j] = e; sum += e;
                }
            }
            sum += __shfl_xor(sum, 16);
            sum += __shfl_xor(sum, 32);
            float inv = 1.0f / sum;
            f32x4 of = zf;
            const int KT2 = (KT + 1) >> 1;
            #pragma unroll
            for (int kt2 = 0; kt2 < 4; ++kt2) if (kt2 < KT2) {
                short8v aV = *(const short8v*)&L[R_VT + (hc + r16) * 128 +
                                                 ((32 * kt2 + 8 * g) ^ cxa)];
                union { short8v v; unsigned u[4]; } pb;
                const int i0 = 2 * kt2, i1 = 2 * kt2 + 1;
                pb.u[0] = pk2(s[i0][0], s[i0][1]);
                pb.u[1] = pk2(s[i0][2], s[i0][3]);
                pb.u[2] = (i1 < KT) ? pk2(s[i1][0], s[i1][1]) : 0u;
                pb.u[3] = (i1 < KT) ? pk2(s[i1][2], s[i1][3]) : 0u;
                of = MFMA(aV, pb.v, of);
            }
            uint2 ov;
            ov.x = pk2(of[0] * inv, of[1] * inv);
            ov.y = pk2(of[2] * inv, of[3] * inv);
            *(uint2*)&L[R_A1 + (16 * qt + r16) * 64 + obc] = ov;
        }
        __syncthreads();   // S4: attention reads done; O visible

        // ---- x += O @ Wo (B direct from global) ----
        #pragma unroll
        for (int kk = 0; kk < 2; ++kk) {
            const int fc = kk ? fc1 : fc0;
            const int gcol = kk ? gc1 : gc0;
            short8v a = *(const short8v*)&L[R_A1 + (16 * w + r16) * 64 + fc];
            #pragma unroll
            for (int ct = 0; ct < 4; ++ct) {
                short8v bb = *(const short8v*)&wog[(16 * ct + r16) * 64 + gcol];
                x[ct] = MFMA(a, bb, x[ct]);
            }
        }
        // ---- LN2(x) -> R_H2 (Q dead after S4; own stripes; no barrier) ----
        #pragma unroll
        for (int j = 0; j < 4; ++j) {
            float s = x[0][j] + x[1][j] + x[2][j] + x[3][j];
            s += __shfl_xor(s, 1); s += __shfl_xor(s, 2);
            s += __shfl_xor(s, 4); s += __shfl_xor(s, 8);
            float m = s * 0.015625f;
            float q = 0.f;
            #pragma unroll
            for (int ct = 0; ct < 4; ++ct) { float d = x[ct][j] - m; q += d * d; }
            q += __shfl_xor(q, 1); q += __shfl_xor(q, 2);
            q += __shfl_xor(q, 4); q += __shfl_xor(q, 8);
            float rs = rsqrtf(q * 0.015625f + 1e-5f);
            #pragma unroll
            for (int ct = 0; ct < 4; ++ct) {
                int col = 16 * ct + r16;
                float hv = (x[ct][j] - m) * rs * lnp[128 + col] + lnp[192 + col];
                L[R_H2 + (16 * w + 4 * g + j) * 64 + (col ^ (cxw | (j << 3)))] = f2bf(hv);
            }
        }

        // ---- FF: x += relu(h2@W1+b1)@W2 + b2 — ZERO barriers (weights from L2,
        //      h2/T are own-wave stripes) ----
        #pragma unroll
        for (int kb = 0; kb < 4; ++kb) {
            f32x4 tacc[4] = {zf, zf, zf, zf};
            #pragma unroll
            for (int kk = 0; kk < 2; ++kk) {
                const int fc = kk ? fc1 : fc0;
                const int gcol = kk ? gc1 : gc0;
                short8v a = *(const short8v*)&L[R_H2 + (16 * w + r16) * 64 + fc];
                #pragma unroll
                for (int ct = 0; ct < 4; ++ct) {
                    short8v bb = *(const short8v*)&w1g[(kb * 64 + 16 * ct + r16) * 64 + gcol];
                    tacc[ct] = MFMA(a, bb, tacc[ct]);
                }
            }
            #pragma unroll
            for (int ct = 0; ct < 4; ++ct)
                #pragma unroll
                for (int j = 0; j < 4; ++j) {
                    float v = fmaxf(tacc[ct][j] + b1f[kb * 64 + 16 * ct + r16], 0.f);
                    L[R_A1 + (16 * w + 4 * g + j) * 64 + ((16 * ct + r16) ^ (cxw | (j << 3)))] = f2bf(v);
                }
            #pragma unroll
            for (int kk = 0; kk < 2; ++kk) {
                const int fc = kk ? fc1 : fc0;
                const int gcol = kk ? gc1 : gc0;
                short8v a = *(const short8v*)&L[R_A1 + (16 * w + r16) * 64 + fc];
                #pragma unroll
                for (int ct = 0; ct < 4; ++ct) {
                    short8v bb = *(const short8v*)&w2g[(16 * ct + r16) * 256 + kb * 64 + gcol];
                    x[ct] = MFMA(a, bb, x[ct]);
                }
            }
        }
        #pragma unroll
        for (int ct = 0; ct < 4; ++ct)
            #pragma unroll
            for (int j = 0; j < 4; ++j) x[ct][j] += b2f[16 * ct + r16];
        __syncthreads();   // S9L: fls/b1f reads done -> next layer phase-0 safe
    }

    // ---- output row x[lidx] -> xrow ----
    if (w == (lidx >> 4) && g == ((lidx >> 2) & 3)) {
        int j = lidx & 3;
        #pragma unroll
        for (int ct = 0; ct < 4; ++ct) {
            float v = (j == 0) ? x[ct][0] : (j == 1) ? x[ct][1] : (j == 2) ? x[ct][2] : x[ct][3];
            xrow[(size_t)b * 64 + 16 * ct + r16] = v;
        }
    }
}

__device__ __forceinline__ float softplusf(float v) {
    return fmaxf(v, 0.f) + log1pf(expf(-fabsf(v)));
}

__global__ __launch_bounds__(256) void policy_kernel(const float* __restrict__ xrow,
        const float* __restrict__ Wp1, const float* __restrict__ bp1,
        const float* __restrict__ Wp2, const float* __restrict__ bp2,
        float* __restrict__ outMu, float* __restrict__ outStd) {
    __shared__ float sx[64];
    __shared__ float sh1[256];
    const int tid = threadIdx.x;
    for (int bi = 0; bi < 16; ++bi) {
        int b = blockIdx.x * 16 + bi;
        if (tid < 64) sx[tid] = xrow[(size_t)b * 64 + tid];
        __syncthreads();
        float acc = bp1[tid];
        #pragma unroll 16
        for (int k = 0; k < 64; ++k) acc = fmaf(sx[k], Wp1[k * 256 + tid], acc);
        sh1[tid] = fmaxf(acc, 0.f);
        __syncthreads();
        if (tid < 224) {
            int j = tid >> 4, gg = tid & 15;
            float a = 0.f;
            #pragma unroll
            for (int kk = 0; kk < 16; ++kk) {
                int k = gg * 16 + kk;
                a = fmaf(sh1[k], Wp2[k * 14 + j], a);
            }
            a += __shfl_xor(a, 1); a += __shfl_xor(a, 2);
            a += __shfl_xor(a, 4); a += __shfl_xor(a, 8);
            if (gg == 0) {
                float pol = a + bp2[j];
                if (j < 7) outStd[(size_t)b * 7 + j] = softplusf(pol);
                else       outMu[(size_t)b * 7 + (j - 7)] = tanhf(pol);
            }
        }
        __syncthreads();
    }
}

extern "C" void kernel_launch(void* const* d_in, const int* in_sizes, int n_in,
                              void* d_out, int out_size, void* d_ws, size_t ws_size,
                              hipStream_t stream) {
    const float* obs   = (const float*)d_in[0];
    const float* seqIn = (const float*)d_in[1];
    const float* mem   = (const float*)d_in[2];
    const int*   len   = (const int*)d_in[3];
    const float* ln_g  = (const float*)d_in[4];
    const float* ln_b  = (const float*)d_in[5];
    const float* Wemb  = (const float*)d_in[6];
    const float* ln1g  = (const float*)d_in[7];
    const float* ln1b  = (const float*)d_in[8];
    const float* ln2g  = (const float*)d_in[9];
    const float* ln2b  = (const float*)d_in[10];
    const float* Wq    = (const float*)d_in[11];
    const float* Wk    = (const float*)d_in[12];
    const float* Wv    = (const float*)d_in[13];
    const float* Wo    = (const float*)d_in[14];
    const float* W1    = (const float*)d_in[15];
    const float* b1    = (const float*)d_in[16];
    const float* W2    = (const float*)d_in[17];
    const float* b2    = (const float*)d_in[18];
    const float* Wp1   = (const float*)d_in[19];
    const float* bp1   = (const float*)d_in[20];
    const float* Wp2   = (const float*)d_in[21];
    const float* bp2   = (const float*)d_in[22];

    float* out    = (float*)d_out;
    float* outMu  = out;
    float* outStd = out + O_STD;
    float* outSeq = out + O_SEQ;
    float* outMem = out + O_MEM;
    float* outLen = out + O_LEN;
    float* xrow   = (float*)d_ws;
    short* wsb    = (short*)((char*)d_ws + 524288);

    hipLaunchKernelGGL(prep_weights, dim3(384), dim3(256), 0, stream,
                       Wq, Wk, Wv, Wo, W1, W2, Wemb, wsb);
    hipLaunchKernelGGL(copy4_kernel, dim3(19200), dim3(256), 0, stream,
                       (const float4*)seqIn, (float4*)outSeq, 4915200);
    hipLaunchKernelGGL(obs_ln_kernel, dim3(512), dim3(256), 0, stream,
                       obs, ln_g, ln_b, len, outSeq, outLen);
    hipLaunchKernelGGL(mega_kernel, dim3(2048), dim3(256), 0, stream,
                       outSeq, mem, len, ln1g, ln1b, ln2g, ln2b, b1, b2,
                       wsb, outMem, xrow);
    hipLaunchKernelGGL(policy_kernel, dim3(128), dim3(256), 0, stream,
                       xrow, Wp1, bp1, Wp2, bp2, outMu, outStd);
}

// Round 17
// 494.006 us; speedup vs baseline: 2.0515x; 1.6170x over previous
//
#include <hip/hip_runtime.h>
#include <hip/hip_bf16.h>
#include <math.h>

// B=2048 S=64 D=6 H=4 DM=64 SS=150 A=7 HID=256 FF=256 DH=16
#define NB 2048

#define LD4(p) (*(const float4*)(p))

// out layout (floats): mu[14336] std[14336] seq[19660800] mem[50331648] len[2048]
#define O_STD 14336
#define O_SEQ 28672
#define O_MEM 19689472
#define O_LEN 70021120

// ws layout: xrow fp32 [2048*64] at byte 0 (512KB); bf16 weights at byte 524288.
#define WQT 0
#define WKT 24576
#define WVT 49152
#define WOT 73728
#define W1T 98304
#define W2T 196608
#define WET 294912

typedef __attribute__((ext_vector_type(8))) short short8v;  // 8 bf16 = 4 VGPRs
typedef __attribute__((ext_vector_type(4))) float f32x4;

#define MFMA(a, b, c) __builtin_amdgcn_mfma_f32_16x16x32_bf16((a), (b), (c), 0, 0, 0)

// 0.25 (attn scale) * log2(e): Q pre-scaled so softmax uses exp2 directly.
#define QSC 0.36067376022224087f

// LDS regions (short indices). Total L[36864] = 72KB (+fls) -> 2 blocks/CU.
#define R_SKV   0       // kv_in: mem rows 0-63 @0, h rows 64-127 @4096; -> K; -> W1 dbuf
#define R_A1    8192    // WqT -> sO -> T
#define R_VT    12288   // WkT @12288, WvT @16384 -> V^T[64][128] spans 12288..20479
#define R_WO    20480   // WoT (dedicated, staged phase 0)
#define R_H2    24576   // sQ (post QK-GEMM) -> LN2 output
#define R_W2B0  28672   // FF W2 chunk dbuf
#define R_W2B1  32768

// HW bf16 convert (RNE).
__device__ __forceinline__ short f2bf(float f) {
    return __builtin_bit_cast(short, (__bf16)f);
}
// packed pair convert: one v_cvt_pk_bf16_f32 (lo -> bits 0-15).
__device__ __forceinline__ unsigned pk2(float lo, float hi) {
    union { __hip_bfloat162 h; unsigned u; } t;
    t.h = __float22bfloat162_rn(make_float2(lo, hi));
    return t.u;
}

// ---------------- prep: fp32 weights -> bf16 transposed in ws ----------------
__global__ __launch_bounds__(256) void prep_weights(
        const float* __restrict__ Wq, const float* __restrict__ Wk,
        const float* __restrict__ Wv, const float* __restrict__ Wo,
        const float* __restrict__ W1, const float* __restrict__ W2,
        const float* __restrict__ Wemb, short* __restrict__ wsb) {
    int idx = blockIdx.x * 256 + threadIdx.x;          // grid covers 98304
    {
        int l = idx >> 14, r = idx & 16383;
        { int n = r >> 6, k = r & 63;
          wsb[W1T + idx] = f2bf(W1[l * 16384 + k * 256 + n]); }
        { int n = r >> 8, k = r & 255;
          wsb[W2T + idx] = f2bf(W2[l * 16384 + k * 64 + n]); }
    }
    if (idx < 24576) {                                  // 4 square mats [64n][64k]
        int l = idx >> 12, r = idx & 4095;
        int n = r >> 6, k = r & 63;
        int s = l * 4096 + k * 64 + n;
        wsb[WQT + idx] = f2bf(Wq[s]);
        wsb[WKT + idx] = f2bf(Wk[s]);
        wsb[WVT + idx] = f2bf(Wv[s]);
        wsb[WOT + idx] = f2bf(Wo[s]);
    }
    if (idx < 10240) {                                  // WembT [64n][160k]
        int n = idx / 160, k = idx - n * 160;
        wsb[WET + idx] = (k < 150) ? f2bf(Wemb[k * 64 + n]) : (short)0;
    }
}

// ---------------- small kernels ----------------
__global__ __launch_bounds__(256) void copy4_kernel(const float4* __restrict__ src,
                                                    float4* __restrict__ dst, int n) {
    int i = blockIdx.x * 256 + threadIdx.x;
    if (i < n) dst[i] = src[i];
}

__global__ __launch_bounds__(256) void obs_ln_kernel(const float* __restrict__ obs,
        const float* __restrict__ g, const float* __restrict__ be,
        const int* __restrict__ len, float* __restrict__ outSeq, float* __restrict__ outLen) {
    int w = threadIdx.x >> 6, lane = threadIdx.x & 63;
    int b = blockIdx.x * 4 + w;
    const float* row = obs + (size_t)b * 150;
    float v0 = row[lane], v1 = row[64 + lane];
    float v2 = (lane < 22) ? row[128 + lane] : 0.f;
    float s = v0 + v1 + v2;
    #pragma unroll
    for (int m = 1; m <= 32; m <<= 1) s += __shfl_xor(s, m);
    float mean = s * (1.0f / 150.0f);
    float d0 = v0 - mean, d1 = v1 - mean;
    float d2 = (lane < 22) ? (v2 - mean) : 0.f;
    float q = d0 * d0 + d1 * d1 + d2 * d2;
    #pragma unroll
    for (int m = 1; m <= 32; m <<= 1) q += __shfl_xor(q, m);
    float rs = rsqrtf(q * (1.0f / 150.0f) + 1e-5f);
    int lenraw = len[b];
    int lidx = min(max(lenraw, 0), 63);
    float* orow = outSeq + ((size_t)lidx * NB + b) * 150;
    orow[lane]      = d0 * rs * g[lane] + be[lane];
    orow[64 + lane] = d1 * rs * g[64 + lane] + be[64 + lane];
    if (lane < 22) orow[128 + lane] = d2 * rs * g[128 + lane] + be[128 + lane];
    if (lane == 0) outLen[b] = (float)((lenraw + 1) & 63);
}

// ---------------- MFMA mega kernel (round-10 structure, 9 barriers/layer) ----------------
__global__ __launch_bounds__(256, 2) void mega_kernel(
        const float* __restrict__ seq, const float* __restrict__ memory,
        const int* __restrict__ len,
        const float* __restrict__ ln1g, const float* __restrict__ ln1b,
        const float* __restrict__ ln2g, const float* __restrict__ ln2b,
        const float* __restrict__ b1, const float* __restrict__ b2,
        const short* __restrict__ wsb,
        float* __restrict__ memOut, float* __restrict__ xrow) {
    __shared__ short L[36864];
    __shared__ float fls[576];
    float* lnp = fls;
    float* b1f = fls + 256;
    float* b2f = fls + 512;

    const int tid = threadIdx.x;
    const int b = blockIdx.x;
    const int w = tid >> 6;
    const int lane = tid & 63;
    const int g = lane >> 4;
    const int r16 = lane & 15;

    const int lenraw = len[b];
    const int lidx = min(max(lenraw, 0), 63);
    const bool reset = (((lenraw + 1) & 63) == 0);

    // hoisted swizzle constants
    const int cxa = (r16 & 7) << 3;            // fragment-read XOR (rows 16X+r16)
    const int fc0 = (8 * g) ^ cxa;             // col offset, kk=0
    const int fc1 = (32 + 8 * g) ^ cxa;        // col offset, kk=1
    const int cxw = (g & 1) << 5;              // D-write XOR base: cxw|(j<<3)
    const int cxm = ((tid >> 2) & 7) << 3;     // mem-stage row XOR

    const short8v zs = {0, 0, 0, 0, 0, 0, 0, 0};
    const f32x4 zf = {0.f, 0.f, 0.f, 0.f};

    // ---------------- embedding: x = seqB(64x150) @ Wemb ----------------
    #pragma unroll 1
    for (int j = 0; j < 16; ++j) {
        int r = w * 16 + j;
        int rb = r * 160;
        const float* srow = seq + ((size_t)r * NB + b) * 150;
        L[rb + lane]      = f2bf(srow[lane]);
        L[rb + 64 + lane] = f2bf(srow[64 + lane]);
        if (lane < 22)      L[rb + 128 + lane] = f2bf(srow[128 + lane]);
        else if (lane < 32) L[rb + 128 + lane] = 0;
    }
    {
        const int4* s4p = (const int4*)(wsb + WET);
        int4* d4p = (int4*)(L + 10240);
        #pragma unroll
        for (int i = 0; i < 5; ++i) d4p[tid + i * 256] = s4p[tid + i * 256];
    }
    __syncthreads();

    f32x4 x[4] = {zf, zf, zf, zf};
    #pragma unroll
    for (int kk = 0; kk < 5; ++kk) {
        short8v a = *(const short8v*)&L[(16 * w + r16) * 160 + kk * 32 + 8 * g];
        #pragma unroll
        for (int ct = 0; ct < 4; ++ct) {
            short8v bb = *(const short8v*)&L[10240 + (16 * ct + r16) * 160 + kk * 32 + 8 * g];
            x[ct] = MFMA(a, bb, x[ct]);
        }
    }
    __syncthreads();

    // ---------------- 6 transformer layers ----------------
    #pragma unroll 1
    for (int l = 0; l < 6; ++l) {
        // staging helpers (int4 domain, SWX pre-swizzle)
        auto stage_sq = [&](const short* src, int dstbase) {
            const int4* s = (const int4*)src;
            int4* d = (int4*)(L + dstbase);
            #pragma unroll
            for (int i = 0; i < 2; ++i) {
                int idx = tid + i * 256;
                d[idx ^ ((idx >> 3) & 7)] = s[idx];
            }
        };
        auto stage_w2 = [&](int kb, int dstbase) {
            int4* d = (int4*)(L + dstbase);
            #pragma unroll
            for (int i = 0; i < 2; ++i) {
                int idx = tid + i * 256;
                int sx = idx ^ ((idx >> 3) & 7);
                int n = idx >> 3, c = idx & 7;
                d[sx] = *(const int4*)&wsb[W2T + l * 16384 + n * 256 + kb * 64 + c * 8];
            }
        };

        // ---- phase 0: stage everything for this layer ----
        if (tid < 64) {
            lnp[tid]       = ln1g[l * 64 + tid];
            lnp[64 + tid]  = ln1b[l * 64 + tid];
            lnp[128 + tid] = ln2g[l * 64 + tid];
            lnp[192 + tid] = ln2b[l * 64 + tid];
            b2f[tid]       = b2[l * 64 + tid];
        }
        b1f[tid] = b1[l * 256 + tid];
        {   // mem -> sKV rows 0..63 (bf16, swizzled) + memOut passthrough
            const float* gmem = memory + ((size_t)l * NB + b) * 4096;
            float* gout = memOut + ((size_t)l * NB + b) * 4096;
            int rr = tid >> 2, c0 = (tid & 3) * 16;
            #pragma unroll
            for (int k4 = 0; k4 < 4; ++k4) {
                float4 v = LD4(&gmem[rr * 64 + c0 + k4 * 4]);
                if (!reset) *(float4*)&gout[rr * 64 + c0 + k4 * 4] = v;
                uint2 su;
                su.x = pk2(v.x, v.y); su.y = pk2(v.z, v.w);
                *(uint2*)&L[rr * 64 + ((c0 + k4 * 4) ^ cxm)] = su;
            }
            if (reset) {
                #pragma unroll
                for (int ct = 0; ct < 4; ++ct)
                    #pragma unroll
                    for (int j = 0; j < 4; ++j)
                        gout[(16 * w + 4 * g + j) * 64 + 16 * ct + r16] = x[ct][j];
            }
        }
        stage_sq(wsb + WQT + l * 4096, R_A1);
        stage_sq(wsb + WKT + l * 4096, R_VT);
        stage_sq(wsb + WVT + l * 4096, R_VT + 4096);
        stage_sq(wsb + WOT + l * 4096, R_WO);
        stage_w2(0, R_W2B0);
        stage_w2(1, R_W2B1);
        __syncthreads();   // S1a: weights + mem staged, lnp visible

        // ---- LN1(x) -> sKV rows 64..127 ----
        // No barrier after LN1: QKV A-operands are own-wave row stripes;
        // cross-lane intra-wave LDS W->R is lgkmcnt-ordered (ff_step idiom).
        #pragma unroll
        for (int j = 0; j < 4; ++j) {
            float s = x[0][j] + x[1][j] + x[2][j] + x[3][j];
            s += __shfl_xor(s, 1); s += __shfl_xor(s, 2);
            s += __shfl_xor(s, 4); s += __shfl_xor(s, 8);
            float m = s * 0.015625f;
            float q = 0.f;
            #pragma unroll
            for (int ct = 0; ct < 4; ++ct) { float d = x[ct][j] - m; q += d * d; }
            q += __shfl_xor(q, 1); q += __shfl_xor(q, 2);
            q += __shfl_xor(q, 4); q += __shfl_xor(q, 8);
            float rs = rsqrtf(q * 0.015625f + 1e-5f);
            #pragma unroll
            for (int ct = 0; ct < 4; ++ct) {
                int col = 16 * ct + r16;
                float hv = (x[ct][j] - m) * rs * lnp[col] + lnp[64 + col];
                L[(64 + 16 * w + 4 * g + j) * 64 + (col ^ (cxw | (j << 3)))] = f2bf(hv);
            }
        }

        // ---- Q + K GEMMs (pass 1) ----
        f32x4 qa[4] = {zf, zf, zf, zf};
        f32x4 ka[2][4] = {{zf, zf, zf, zf}, {zf, zf, zf, zf}};
        #pragma unroll
        for (int kk = 0; kk < 2; ++kk) {
            const int fc = kk ? fc1 : fc0;
            short8v ah = *(const short8v*)&L[(64 + 16 * w + r16) * 64 + fc];
            short8v a0 = *(const short8v*)&L[(16 * w + r16) * 64 + fc];
            #pragma unroll
            for (int ct = 0; ct < 4; ++ct) {
                short8v bq = *(const short8v*)&L[R_A1 + (16 * ct + r16) * 64 + fc];
                short8v bk = *(const short8v*)&L[R_VT + (16 * ct + r16) * 64 + fc];
                qa[ct]    = MFMA(ah, bq, qa[ct]);
                ka[0][ct] = MFMA(a0, bk, ka[0][ct]);
                ka[1][ct] = MFMA(ah, bk, ka[1][ct]);
            }
        }
        // pack Q -> R_H2 (dead region) — no barrier; visibility via S2b+S3.
        #pragma unroll
        for (int ct = 0; ct < 4; ++ct)
            #pragma unroll
            for (int j = 0; j < 4; ++j)
                L[R_H2 + (16 * w + 4 * g + j) * 64 + ((16 * ct + r16) ^ (cxw | (j << 3)))] =
                    f2bf(qa[ct][j] * QSC);

        // ---- V GEMM (pass 2) ----
        f32x4 va[2][4] = {{zf, zf, zf, zf}, {zf, zf, zf, zf}};
        #pragma unroll
        for (int kk = 0; kk < 2; ++kk) {
            const int fc = kk ? fc1 : fc0;
            short8v ah = *(const short8v*)&L[(64 + 16 * w + r16) * 64 + fc];
            short8v a0 = *(const short8v*)&L[(16 * w + r16) * 64 + fc];
            #pragma unroll
            for (int ct = 0; ct < 4; ++ct) {
                short8v bv = *(const short8v*)&L[R_VT + 4096 + (16 * ct + r16) * 64 + fc];
                va[0][ct] = MFMA(a0, bv, va[0][ct]);
                va[1][ct] = MFMA(ah, bv, va[1][ct]);
            }
        }
        __syncthreads();   // S2b: sKV A-reads + WkT/WvT B-reads done

        // pack K -> R_SKV and V -> R_VT as permuted V^T (vector b64)
        #pragma unroll
        for (int ct = 0; ct < 4; ++ct) {
            #pragma unroll
            for (int j = 0; j < 4; ++j) {
                int key0 = 16 * w + 4 * g + j;
                int colw = (16 * ct + r16) ^ (cxw | (j << 3));
                L[key0 * 64 + colw] = f2bf(ka[0][ct][j]);
                L[(64 + key0) * 64 + colw] = f2bf(ka[1][ct][j]);
            }
        }
        {
            const int p0 = ((w >> 1) << 5) | (g << 3) | ((w & 1) << 2);  // perm(key0)
            const int p1 = p0 | 64;                                       // perm(key0+64)
            #pragma unroll
            for (int ct = 0; ct < 4; ++ct) {
                int rowb = R_VT + (16 * ct + r16) * 128;
                uint2 v0, v1;
                v0.x = pk2(va[0][ct][0], va[0][ct][1]);
                v0.y = pk2(va[0][ct][2], va[0][ct][3]);
                v1.x = pk2(va[1][ct][0], va[1][ct][1]);
                v1.y = pk2(va[1][ct][2], va[1][ct][3]);
                *(uint2*)&L[rowb + (p0 ^ cxa)] = v0;
                *(uint2*)&L[rowb + (p1 ^ cxa)] = v1;
            }
        }
        __syncthreads();   // S3

        // ---- attention: wave w = head; causal-skipped blocks, no-max exp2 softmax ----
        const int hc = 16 * w;
        const int attc = (hc + 8 * g) ^ cxa;       // bQ/aK col
        const int obc  = (hc + 4 * g) ^ cxa;       // O write col base
        #pragma unroll
        for (int qt = 0; qt < 4; ++qt) {
            const int KT = 5 + qt;                 // live key blocks (kt < KT)
            short8v bQ = (g < 2) ? *(const short8v*)&L[R_H2 + (16 * qt + r16) * 64 + attc] : zs;
            f32x4 s[8];
            #pragma unroll
            for (int kt = 0; kt < 8; ++kt) if (kt < KT) {
                short8v aK = *(const short8v*)&L[(16 * kt + r16) * 64 + attc];
                s[kt] = MFMA(aK, bQ, zf);
            }
            float sum = 0.f;
            #pragma unroll
            for (int kt = 0; kt < 8; ++kt) if (kt < KT) {
                #pragma unroll
                for (int j = 0; j < 4; ++j) {
                    float e = exp2f(s[kt][j]);     // Q pre-scaled; bounded, no max needed
                    if (kt == KT - 1) e = ((4 * g + j) > r16) ? 0.f : e;  // causal edge
                    s[kt][j] = e; sum += e;
                }
            }
            sum += __shfl_xor(sum, 16);
            sum += __shfl_xor(sum, 32);
            float inv = 1.0f / sum;
            f32x4 of = zf;
            const int KT2 = (KT + 1) >> 1;
            #pragma unroll
            for (int kt2 = 0; kt2 < 4; ++kt2) if (kt2 < KT2) {
                short8v aV = *(const short8v*)&L[R_VT + (hc + r16) * 128 +
                                                 ((32 * kt2 + 8 * g) ^ cxa)];
                union { short8v v; unsigned u[4]; } pb;
                const int i0 = 2 * kt2, i1 = 2 * kt2 + 1;
                pb.u[0] = pk2(s[i0][0], s[i0][1]);
                pb.u[1] = pk2(s[i0][2], s[i0][3]);
                pb.u[2] = (i1 < KT) ? pk2(s[i1][0], s[i1][1]) : 0u;
                pb.u[3] = (i1 < KT) ? pk2(s[i1][2], s[i1][3]) : 0u;
                of = MFMA(aV, pb.v, of);
            }
            uint2 ov;
            ov.x = pk2(of[0] * inv, of[1] * inv);
            ov.y = pk2(of[2] * inv, of[3] * inv);
            // O -> R_A1 (over WqT; WqT reads ended before S2b)
            *(uint2*)&L[R_A1 + (16 * qt + r16) * 64 + obc] = ov;
        }
        __syncthreads();   // S4: attention reads of K/Q/V^T done; O visible

        // ---- issue FF W1 kb0/kb1 stages into dead K region (hidden under Wo+LN2) ----
        stage_sq(wsb + W1T + l * 16384, R_SKV);              // W1(0) -> 0..4095
        stage_sq(wsb + W1T + l * 16384 + 4096, R_SKV + 4096); // W1(1) -> 4096..8191

        // ---- x += O @ Wo (WoT pre-staged at R_WO; no extra barrier) ----
        #pragma unroll
        for (int kk = 0; kk < 2; ++kk) {
            const int fc = kk ? fc1 : fc0;
            short8v a = *(const short8v*)&L[R_A1 + (16 * w + r16) * 64 + fc];
            #pragma unroll
            for (int ct = 0; ct < 4; ++ct) {
                short8v bb = *(const short8v*)&L[R_WO + (16 * ct + r16) * 64 + fc];
                x[ct] = MFMA(a, bb, x[ct]);
            }
        }
        // ---- LN2(x) -> R_H2 (Q dead after S4; intra-wave stripes, no barrier) ----
        #pragma unroll
        for (int j = 0; j < 4; ++j) {
            float s = x[0][j] + x[1][j] + x[2][j] + x[3][j];
            s += __shfl_xor(s, 1); s += __shfl_xor(s, 2);
            s += __shfl_xor(s, 4); s += __shfl_xor(s, 8);
            float m = s * 0.015625f;
            float q = 0.f;
            #pragma unroll
            for (int ct = 0; ct < 4; ++ct) { float d = x[ct][j] - m; q += d * d; }
            q += __shfl_xor(q, 1); q += __shfl_xor(q, 2);
            q += __shfl_xor(q, 4); q += __shfl_xor(q, 8);
            float rs = rsqrtf(q * 0.015625f + 1e-5f);
            #pragma unroll
            for (int ct = 0; ct < 4; ++ct) {
                int col = 16 * ct + r16;
                float hv = (x[ct][j] - m) * rs * lnp[128 + col] + lnp[192 + col];
                L[R_H2 + (16 * w + 4 * g + j) * 64 + (col ^ (cxw | (j << 3)))] = f2bf(hv);
            }
        }

        // ---- FF: x += relu(h2@W1+b1)@W2, double-buffered, 1 barrier per kb ----
        auto ff_step = [&](int w1b, int w2b, int kb) {
            f32x4 tacc[4] = {zf, zf, zf, zf};
            #pragma unroll
            for (int kk = 0; kk < 2; ++kk) {
                const int fc = kk ? fc1 : fc0;
                short8v a = *(const short8v*)&L[R_H2 + (16 * w + r16) * 64 + fc];
                #pragma unroll
                for (int ct = 0; ct < 4; ++ct) {
                    short8v bb = *(const short8v*)&L[w1b + (16 * ct + r16) * 64 + fc];
                    tacc[ct] = MFMA(a, bb, tacc[ct]);
                }
            }
            // T pack over R_A1 (row-stripe local -> intra-wave)
            #pragma unroll
            for (int ct = 0; ct < 4; ++ct)
                #pragma unroll
                for (int j = 0; j < 4; ++j) {
                    float v = fmaxf(tacc[ct][j] + b1f[kb * 64 + 16 * ct + r16], 0.f);
                    L[R_A1 + (16 * w + 4 * g + j) * 64 + ((16 * ct + r16) ^ (cxw | (j << 3)))] = f2bf(v);
                }
            #pragma unroll
            for (int kk = 0; kk < 2; ++kk) {
                const int fc = kk ? fc1 : fc0;
                short8v a = *(const short8v*)&L[R_A1 + (16 * w + r16) * 64 + fc];
                #pragma unroll
                for (int ct = 0; ct < 4; ++ct) {
                    short8v bb = *(const short8v*)&L[w2b + (16 * ct + r16) * 64 + fc];
                    x[ct] = MFMA(a, bb, x[ct]);
                }
            }
        };

        __syncthreads();   // Sff0: W1(0)/W1(1) staged; T-over-O safe (all Wo reads done)
        ff_step(R_SKV, R_W2B0, 0);
        __syncthreads();   // Sff1: kb0 reads of buf0 done
        stage_sq(wsb + W1T + l * 16384 + 2 * 4096, R_SKV);   // W1(2) -> buf0
        stage_w2(2, R_W2B0);                                  // W2(2) -> buf0
        ff_step(R_SKV + 4096, R_W2B1, 1);
        __syncthreads();   // Sff2: kb1 reads of buf1 done; kb2 stages complete
        stage_sq(wsb + W1T + l * 16384 + 3 * 4096, R_SKV + 4096); // W1(3) -> buf1
        stage_w2(3, R_W2B1);                                  // W2(3) -> buf1
        ff_step(R_SKV, R_W2B0, 2);
        __syncthreads();   // Sff3: kb3 stages complete
        ff_step(R_SKV + 4096, R_W2B1, 3);
        #pragma unroll
        for (int ct = 0; ct < 4; ++ct)
            #pragma unroll
            for (int j = 0; j < 4; ++j) x[ct][j] += b2f[16 * ct + r16];
        __syncthreads();   // S9L: kb3 reads done -> next layer phase-0 stages safe
    }

    // ---- output row x[lidx] -> xrow ----
    if (w == (lidx >> 4) && g == ((lidx >> 2) & 3)) {
        int j = lidx & 3;
        #pragma unroll
        for (int ct = 0; ct < 4; ++ct) {
            float v = (j == 0) ? x[ct][0] : (j == 1) ? x[ct][1] : (j == 2) ? x[ct][2] : x[ct][3];
            xrow[(size_t)b * 64 + 16 * ct + r16] = v;
        }
    }
}

__device__ __forceinline__ float softplusf(float v) {
    return fmaxf(v, 0.f) + log1pf(expf(-fabsf(v)));
}

__global__ __launch_bounds__(256) void policy_kernel(const float* __restrict__ xrow,
        const float* __restrict__ Wp1, const float* __restrict__ bp1,
        const float* __restrict__ Wp2, const float* __restrict__ bp2,
        float* __restrict__ outMu, float* __restrict__ outStd) {
    __shared__ float sx[64];
    __shared__ float sh1[256];
    const int tid = threadIdx.x;
    for (int bi = 0; bi < 16; ++bi) {
        int b = blockIdx.x * 16 + bi;
        if (tid < 64) sx[tid] = xrow[(size_t)b * 64 + tid];
        __syncthreads();
        float acc = bp1[tid];
        #pragma unroll 16
        for (int k = 0; k < 64; ++k) acc = fmaf(sx[k], Wp1[k * 256 + tid], acc);
        sh1[tid] = fmaxf(acc, 0.f);
        __syncthreads();
        if (tid < 224) {
            int j = tid >> 4, gg = tid & 15;
            float a = 0.f;
            #pragma unroll
            for (int kk = 0; kk < 16; ++kk) {
                int k = gg * 16 + kk;
                a = fmaf(sh1[k], Wp2[k * 14 + j], a);
            }
            a += __shfl_xor(a, 1); a += __shfl_xor(a, 2);
            a += __shfl_xor(a, 4); a += __shfl_xor(a, 8);
            if (gg == 0) {
                float pol = a + bp2[j];
                if (j < 7) outStd[(size_t)b * 7 + j] = softplusf(pol);
                else       outMu[(size_t)b * 7 + (j - 7)] = tanhf(pol);
            }
        }
        __syncthreads();
    }
}

extern "C" void kernel_launch(void* const* d_in, const int* in_sizes, int n_in,
                              void* d_out, int out_size, void* d_ws, size_t ws_size,
                              hipStream_t stream) {
    const float* obs   = (const float*)d_in[0];
    const float* seqIn = (const float*)d_in[1];
    const float* mem   = (const float*)d_in[2];
    const int*   len   = (const int*)d_in[3];
    const float* ln_g  = (const float*)d_in[4];
    const float* ln_b  = (const float*)d_in[5];
    const float* Wemb  = (const float*)d_in[6];
    const float* ln1g  = (const float*)d_in[7];
    const float* ln1b  = (const float*)d_in[8];
    const float* ln2g  = (const float*)d_in[9];
    const float* ln2b  = (const float*)d_in[10];
    const float* Wq    = (const float*)d_in[11];
    const float* Wk    = (const float*)d_in[12];
    const float* Wv    = (const float*)d_in[13];
    const float* Wo    = (const float*)d_in[14];
    const float* W1    = (const float*)d_in[15];
    const float* b1    = (const float*)d_in[16];
    const float* W2    = (const float*)d_in[17];
    const float* b2    = (const float*)d_in[18];
    const float* Wp1   = (const float*)d_in[19];
    const float* bp1   = (const float*)d_in[20];
    const float* Wp2   = (const float*)d_in[21];
    const float* bp2   = (const float*)d_in[22];

    float* out    = (float*)d_out;
    float* outMu  = out;
    float* outStd = out + O_STD;
    float* outSeq = out + O_SEQ;
    float* outMem = out + O_MEM;
    float* outLen = out + O_LEN;
    float* xrow   = (float*)d_ws;
    short* wsb    = (short*)((char*)d_ws + 524288);

    hipLaunchKernelGGL(prep_weights, dim3(384), dim3(256), 0, stream,
                       Wq, Wk, Wv, Wo, W1, W2, Wemb, wsb);
    hipLaunchKernelGGL(copy4_kernel, dim3(19200), dim3(256), 0, stream,
                       (const float4*)seqIn, (float4*)outSeq, 4915200);
    hipLaunchKernelGGL(obs_ln_kernel, dim3(512), dim3(256), 0, stream,
                       obs, ln_g, ln_b, len, outSeq, outLen);
    hipLaunchKernelGGL(mega_kernel, dim3(2048), dim3(256), 0, stream,
                       outSeq, mem, len, ln1g, ln1b, ln2g, ln2b, b1, b2,
                       wsb, outMem, xrow);
    hipLaunchKernelGGL(policy_kernel, dim3(128), dim3(256), 0, stream,
                       xrow, Wp1, bp1, Wp2, bp2, outMu, outStd);
}

// Round 18
// 441.373 us; speedup vs baseline: 2.2961x; 1.1192x over previous
//
#include <hip/hip_runtime.h>
#include <hip/hip_bf16.h>
#include <math.h>

// B=2048 S=64 D=6 H=4 DM=64 SS=150 A=7 HID=256 FF=256 DH=16
#define NB 2048

#define LD4(p) (*(const float4*)(p))

// out layout (floats): mu[14336] std[14336] seq[19660800] mem[50331648] len[2048]
#define O_STD 14336
#define O_SEQ 28672
#define O_MEM 19689472
#define O_LEN 70021120

// ws layout: bf16 weights at byte 524288 (xrow slot retired, kept for layout stability).
#define WQT 0
#define WKT 24576
#define WVT 49152
#define WOT 73728
#define W1T 98304
#define W2T 196608
#define WET 294912

typedef __attribute__((ext_vector_type(8))) short short8v;  // 8 bf16 = 4 VGPRs
typedef __attribute__((ext_vector_type(4))) float f32x4;

#define MFMA(a, b, c) __builtin_amdgcn_mfma_f32_16x16x32_bf16((a), (b), (c), 0, 0, 0)

// 0.25 (attn scale) * log2(e): Q pre-scaled so softmax uses exp2 directly.
#define QSC 0.36067376022224087f

// LDS regions (short indices). Total L[36864] = 72KB (+fls) -> 2 blocks/CU.
#define R_SKV   0       // kv_in: mem rows 0-63 @0, h rows 64-127 @4096; -> K; -> W1 dbuf
#define R_A1    8192    // WqT -> sO -> T
#define R_VT    12288   // WkT @12288, WvT @16384 -> V^T[64][128] spans 12288..20479
#define R_WO    20480   // WoT (dedicated, staged phase 0)
#define R_H2    24576   // sQ (post QK-GEMM) -> LN2 output
#define R_W2B0  28672   // FF W2 chunk dbuf
#define R_W2B1  32768

// HW bf16 convert (RNE).
__device__ __forceinline__ short f2bf(float f) {
    return __builtin_bit_cast(short, (__bf16)f);
}
// packed pair convert: one v_cvt_pk_bf16_f32 (lo -> bits 0-15).
__device__ __forceinline__ unsigned pk2(float lo, float hi) {
    union { __hip_bfloat162 h; unsigned u; } t;
    t.h = __float22bfloat162_rn(make_float2(lo, hi));
    return t.u;
}

__device__ __forceinline__ float softplusf(float v) {
    return fmaxf(v, 0.f) + log1pf(expf(-fabsf(v)));
}

// ---------------- prep: fp32 weights -> bf16 transposed in ws ----------------
__global__ __launch_bounds__(256) void prep_weights(
        const float* __restrict__ Wq, const float* __restrict__ Wk,
        const float* __restrict__ Wv, const float* __restrict__ Wo,
        const float* __restrict__ W1, const float* __restrict__ W2,
        const float* __restrict__ Wemb, short* __restrict__ wsb) {
    int idx = blockIdx.x * 256 + threadIdx.x;          // grid covers 98304
    {
        int l = idx >> 14, r = idx & 16383;
        { int n = r >> 6, k = r & 63;
          wsb[W1T + idx] = f2bf(W1[l * 16384 + k * 256 + n]); }
        { int n = r >> 8, k = r & 255;
          wsb[W2T + idx] = f2bf(W2[l * 16384 + k * 64 + n]); }
    }
    if (idx < 24576) {                                  // 4 square mats [64n][64k]
        int l = idx >> 12, r = idx & 4095;
        int n = r >> 6, k = r & 63;
        int s = l * 4096 + k * 64 + n;
        wsb[WQT + idx] = f2bf(Wq[s]);
        wsb[WKT + idx] = f2bf(Wk[s]);
        wsb[WVT + idx] = f2bf(Wv[s]);
        wsb[WOT + idx] = f2bf(Wo[s]);
    }
    if (idx < 10240) {                                  // WembT [64n][160k]
        int n = idx / 160, k = idx - n * 160;
        wsb[WET + idx] = (k < 150) ? f2bf(Wemb[k * 64 + n]) : (short)0;
    }
}

// ---------------- obs LN (writes the lidx row of outSeq + new_length) ----------------
__global__ __launch_bounds__(256) void obs_ln_kernel(const float* __restrict__ obs,
        const float* __restrict__ g, const float* __restrict__ be,
        const int* __restrict__ len, float* __restrict__ outSeq, float* __restrict__ outLen) {
    int w = threadIdx.x >> 6, lane = threadIdx.x & 63;
    int b = blockIdx.x * 4 + w;
    const float* row = obs + (size_t)b * 150;
    float v0 = row[lane], v1 = row[64 + lane];
    float v2 = (lane < 22) ? row[128 + lane] : 0.f;
    float s = v0 + v1 + v2;
    #pragma unroll
    for (int m = 1; m <= 32; m <<= 1) s += __shfl_xor(s, m);
    float mean = s * (1.0f / 150.0f);
    float d0 = v0 - mean, d1 = v1 - mean;
    float d2 = (lane < 22) ? (v2 - mean) : 0.f;
    float q = d0 * d0 + d1 * d1 + d2 * d2;
    #pragma unroll
    for (int m = 1; m <= 32; m <<= 1) q += __shfl_xor(q, m);
    float rs = rsqrtf(q * (1.0f / 150.0f) + 1e-5f);
    int lenraw = len[b];
    int lidx = min(max(lenraw, 0), 63);
    float* orow = outSeq + ((size_t)lidx * NB + b) * 150;
    orow[lane]      = d0 * rs * g[lane] + be[lane];
    orow[64 + lane] = d1 * rs * g[64 + lane] + be[64 + lane];
    if (lane < 22) orow[128 + lane] = d2 * rs * g[128 + lane] + be[128 + lane];
    if (lane == 0) outLen[b] = (float)((lenraw + 1) & 63);
}

// ---------------- MFMA mega kernel (r17 loop + seq-copy fold + policy epilogue) ----------------
__global__ __launch_bounds__(256, 2) void mega_kernel(
        const float* __restrict__ seqIn,    // original sequence (B input)
        float* __restrict__ outSeq,         // seq output; row lidx pre-written by obs_ln
        const float* __restrict__ memory,
        const int* __restrict__ len,
        const float* __restrict__ ln1g, const float* __restrict__ ln1b,
        const float* __restrict__ ln2g, const float* __restrict__ ln2b,
        const float* __restrict__ b1, const float* __restrict__ b2,
        const short* __restrict__ wsb,
        const float* __restrict__ Wp1, const float* __restrict__ bp1,
        const float* __restrict__ Wp2, const float* __restrict__ bp2,
        float* __restrict__ memOut,
        float* __restrict__ outMu, float* __restrict__ outStd) {
    __shared__ short L[36864];
    __shared__ float fls[576];
    float* lnp = fls;
    float* b1f = fls + 256;
    float* b2f = fls + 512;

    const int tid = threadIdx.x;
    const int b = blockIdx.x;
    const int w = tid >> 6;
    const int lane = tid & 63;
    const int g = lane >> 4;
    const int r16 = lane & 15;

    const int lenraw = len[b];
    const int lidx = min(max(lenraw, 0), 63);
    const bool reset = (((lenraw + 1) & 63) == 0);

    // hoisted swizzle constants
    const int cxa = (r16 & 7) << 3;            // fragment-read XOR (rows 16X+r16)
    const int fc0 = (8 * g) ^ cxa;             // col offset, kk=0
    const int fc1 = (32 + 8 * g) ^ cxa;        // col offset, kk=1
    const int cxw = (g & 1) << 5;              // D-write XOR base: cxw|(j<<3)
    const int cxm = ((tid >> 2) & 7) << 3;     // mem-stage row XOR

    const short8v zs = {0, 0, 0, 0, 0, 0, 0, 0};
    const f32x4 zf = {0.f, 0.f, 0.f, 0.f};

    // ---------------- embedding + inline seq copy ----------------
    // Row lidx comes from outSeq (obs_ln wrote it); others from seqIn and are
    // copied to outSeq here (copy4 kernel eliminated).
    #pragma unroll 1
    for (int j = 0; j < 16; ++j) {
        int r = w * 16 + j;
        int rb = r * 160;
        const size_t ro = ((size_t)r * NB + b) * 150;
        const float* srow = (r == lidx) ? (outSeq + ro) : (seqIn + ro);
        float v0 = srow[lane];
        float v1 = srow[64 + lane];
        float v2 = (lane < 22) ? srow[128 + lane] : 0.f;
        if (r != lidx) {
            float* orow = outSeq + ro;
            orow[lane]      = v0;
            orow[64 + lane] = v1;
            if (lane < 22) orow[128 + lane] = v2;
        }
        L[rb + lane]      = f2bf(v0);
        L[rb + 64 + lane] = f2bf(v1);
        if (lane < 32) L[rb + 128 + lane] = (lane < 22) ? f2bf(v2) : (short)0;
    }
    {
        const int4* s4p = (const int4*)(wsb + WET);
        int4* d4p = (int4*)(L + 10240);
        #pragma unroll
        for (int i = 0; i < 5; ++i) d4p[tid + i * 256] = s4p[tid + i * 256];
    }
    __syncthreads();

    f32x4 x[4] = {zf, zf, zf, zf};
    #pragma unroll
    for (int kk = 0; kk < 5; ++kk) {
        short8v a = *(const short8v*)&L[(16 * w + r16) * 160 + kk * 32 + 8 * g];
        #pragma unroll
        for (int ct = 0; ct < 4; ++ct) {
            short8v bb = *(const short8v*)&L[10240 + (16 * ct + r16) * 160 + kk * 32 + 8 * g];
            x[ct] = MFMA(a, bb, x[ct]);
        }
    }
    __syncthreads();

    // ---------------- 6 transformer layers (r17-proven body) ----------------
    #pragma unroll 1
    for (int l = 0; l < 6; ++l) {
        auto stage_sq = [&](const short* src, int dstbase) {
            const int4* s = (const int4*)src;
            int4* d = (int4*)(L + dstbase);
            #pragma unroll
            for (int i = 0; i < 2; ++i) {
                int idx = tid + i * 256;
                d[idx ^ ((idx >> 3) & 7)] = s[idx];
            }
        };
        auto stage_w2 = [&](int kb, int dstbase) {
            int4* d = (int4*)(L + dstbase);
            #pragma unroll
            for (int i = 0; i < 2; ++i) {
                int idx = tid + i * 256;
                int sx = idx ^ ((idx >> 3) & 7);
                int n = idx >> 3, c = idx & 7;
                d[sx] = *(const int4*)&wsb[W2T + l * 16384 + n * 256 + kb * 64 + c * 8];
            }
        };

        // ---- phase 0: stage everything for this layer ----
        if (tid < 64) {
            lnp[tid]       = ln1g[l * 64 + tid];
            lnp[64 + tid]  = ln1b[l * 64 + tid];
            lnp[128 + tid] = ln2g[l * 64 + tid];
            lnp[192 + tid] = ln2b[l * 64 + tid];
            b2f[tid]       = b2[l * 64 + tid];
        }
        b1f[tid] = b1[l * 256 + tid];
        {   // mem -> sKV rows 0..63 (bf16, swizzled) + memOut passthrough
            const float* gmem = memory + ((size_t)l * NB + b) * 4096;
            float* gout = memOut + ((size_t)l * NB + b) * 4096;
            int rr = tid >> 2, c0 = (tid & 3) * 16;
            #pragma unroll
            for (int k4 = 0; k4 < 4; ++k4) {
                float4 v = LD4(&gmem[rr * 64 + c0 + k4 * 4]);
                if (!reset) *(float4*)&gout[rr * 64 + c0 + k4 * 4] = v;
                uint2 su;
                su.x = pk2(v.x, v.y); su.y = pk2(v.z, v.w);
                *(uint2*)&L[rr * 64 + ((c0 + k4 * 4) ^ cxm)] = su;
            }
            if (reset) {
                #pragma unroll
                for (int ct = 0; ct < 4; ++ct)
                    #pragma unroll
                    for (int j = 0; j < 4; ++j)
                        gout[(16 * w + 4 * g + j) * 64 + 16 * ct + r16] = x[ct][j];
            }
        }
        stage_sq(wsb + WQT + l * 4096, R_A1);
        stage_sq(wsb + WKT + l * 4096, R_VT);
        stage_sq(wsb + WVT + l * 4096, R_VT + 4096);
        stage_sq(wsb + WOT + l * 4096, R_WO);
        stage_w2(0, R_W2B0);
        stage_w2(1, R_W2B1);
        __syncthreads();   // S1a

        // ---- LN1(x) -> sKV rows 64..127 (no barrier; own-wave stripes) ----
        #pragma unroll
        for (int j = 0; j < 4; ++j) {
            float s = x[0][j] + x[1][j] + x[2][j] + x[3][j];
            s += __shfl_xor(s, 1); s += __shfl_xor(s, 2);
            s += __shfl_xor(s, 4); s += __shfl_xor(s, 8);
            float m = s * 0.015625f;
            float q = 0.f;
            #pragma unroll
            for (int ct = 0; ct < 4; ++ct) { float d = x[ct][j] - m; q += d * d; }
            q += __shfl_xor(q, 1); q += __shfl_xor(q, 2);
            q += __shfl_xor(q, 4); q += __shfl_xor(q, 8);
            float rs = rsqrtf(q * 0.015625f + 1e-5f);
            #pragma unroll
            for (int ct = 0; ct < 4; ++ct) {
                int col = 16 * ct + r16;
                float hv = (x[ct][j] - m) * rs * lnp[col] + lnp[64 + col];
                L[(64 + 16 * w + 4 * g + j) * 64 + (col ^ (cxw | (j << 3)))] = f2bf(hv);
            }
        }

        // ---- Q + K GEMMs (pass 1) ----
        f32x4 qa[4] = {zf, zf, zf, zf};
        f32x4 ka[2][4] = {{zf, zf, zf, zf}, {zf, zf, zf, zf}};
        #pragma unroll
        for (int kk = 0; kk < 2; ++kk) {
            const int fc = kk ? fc1 : fc0;
            short8v ah = *(const short8v*)&L[(64 + 16 * w + r16) * 64 + fc];
            short8v a0 = *(const short8v*)&L[(16 * w + r16) * 64 + fc];
            #pragma unroll
            for (int ct = 0; ct < 4; ++ct) {
                short8v bq = *(const short8v*)&L[R_A1 + (16 * ct + r16) * 64 + fc];
                short8v bk = *(const short8v*)&L[R_VT + (16 * ct + r16) * 64 + fc];
                qa[ct]    = MFMA(ah, bq, qa[ct]);
                ka[0][ct] = MFMA(a0, bk, ka[0][ct]);
                ka[1][ct] = MFMA(ah, bk, ka[1][ct]);
            }
        }
        // pack Q -> R_H2 (dead region) — no barrier; visibility via S2b+S3.
        #pragma unroll
        for (int ct = 0; ct < 4; ++ct)
            #pragma unroll
            for (int j = 0; j < 4; ++j)
                L[R_H2 + (16 * w + 4 * g + j) * 64 + ((16 * ct + r16) ^ (cxw | (j << 3)))] =
                    f2bf(qa[ct][j] * QSC);

        // ---- V GEMM (pass 2) ----
        f32x4 va[2][4] = {{zf, zf, zf, zf}, {zf, zf, zf, zf}};
        #pragma unroll
        for (int kk = 0; kk < 2; ++kk) {
            const int fc = kk ? fc1 : fc0;
            short8v ah = *(const short8v*)&L[(64 + 16 * w + r16) * 64 + fc];
            short8v a0 = *(const short8v*)&L[(16 * w + r16) * 64 + fc];
            #pragma unroll
            for (int ct = 0; ct < 4; ++ct) {
                short8v bv = *(const short8v*)&L[R_VT + 4096 + (16 * ct + r16) * 64 + fc];
                va[0][ct] = MFMA(a0, bv, va[0][ct]);
                va[1][ct] = MFMA(ah, bv, va[1][ct]);
            }
        }
        __syncthreads();   // S2b: sKV A-reads + WkT/WvT B-reads done

        // pack K -> R_SKV and V -> R_VT as permuted V^T (vector b64)
        #pragma unroll
        for (int ct = 0; ct < 4; ++ct) {
            #pragma unroll
            for (int j = 0; j < 4; ++j) {
                int key0 = 16 * w + 4 * g + j;
                int colw = (16 * ct + r16) ^ (cxw | (j << 3));
                L[key0 * 64 + colw] = f2bf(ka[0][ct][j]);
                L[(64 + key0) * 64 + colw] = f2bf(ka[1][ct][j]);
            }
        }
        {
            const int p0 = ((w >> 1) << 5) | (g << 3) | ((w & 1) << 2);  // perm(key0)
            const int p1 = p0 | 64;                                       // perm(key0+64)
            #pragma unroll
            for (int ct = 0; ct < 4; ++ct) {
                int rowb = R_VT + (16 * ct + r16) * 128;
                uint2 v0, v1;
                v0.x = pk2(va[0][ct][0], va[0][ct][1]);
                v0.y = pk2(va[0][ct][2], va[0][ct][3]);
                v1.x = pk2(va[1][ct][0], va[1][ct][1]);
                v1.y = pk2(va[1][ct][2], va[1][ct][3]);
                *(uint2*)&L[rowb + (p0 ^ cxa)] = v0;
                *(uint2*)&L[rowb + (p1 ^ cxa)] = v1;
            }
        }
        __syncthreads();   // S3

        // ---- attention: wave w = head; causal-skipped blocks, no-max exp2 softmax ----
        const int hc = 16 * w;
        const int attc = (hc + 8 * g) ^ cxa;       // bQ/aK col
        const int obc  = (hc + 4 * g) ^ cxa;       // O write col base
        #pragma unroll
        for (int qt = 0; qt < 4; ++qt) {
            const int KT = 5 + qt;                 // live key blocks (kt < KT)
            short8v bQ = (g < 2) ? *(const short8v*)&L[R_H2 + (16 * qt + r16) * 64 + attc] : zs;
            f32x4 s[8];
            #pragma unroll
            for (int kt = 0; kt < 8; ++kt) if (kt < KT) {
                short8v aK = *(const short8v*)&L[(16 * kt + r16) * 64 + attc];
                s[kt] = MFMA(aK, bQ, zf);
            }
            float sum = 0.f;
            #pragma unroll
            for (int kt = 0; kt < 8; ++kt) if (kt < KT) {
                #pragma unroll
                for (int j = 0; j < 4; ++j) {
                    float e = exp2f(s[kt][j]);     // Q pre-scaled; bounded, no max needed
                    if (kt == KT - 1) e = ((4 * g + j) > r16) ? 0.f : e;  // causal edge
                    s[kt][j] = e; sum += e;
                }
            }
            sum += __shfl_xor(sum, 16);
            sum += __shfl_xor(sum, 32);
            float inv = 1.0f / sum;
            f32x4 of = zf;
            const int KT2 = (KT + 1) >> 1;
            #pragma unroll
            for (int kt2 = 0; kt2 < 4; ++kt2) if (kt2 < KT2) {
                short8v aV = *(const short8v*)&L[R_VT + (hc + r16) * 128 +
                                                 ((32 * kt2 + 8 * g) ^ cxa)];
                union { short8v v; unsigned u[4]; } pb;
                const int i0 = 2 * kt2, i1 = 2 * kt2 + 1;
                pb.u[0] = pk2(s[i0][0], s[i0][1]);
                pb.u[1] = pk2(s[i0][2], s[i0][3]);
                pb.u[2] = (i1 < KT) ? pk2(s[i1][0], s[i1][1]) : 0u;
                pb.u[3] = (i1 < KT) ? pk2(s[i1][2], s[i1][3]) : 0u;
                of = MFMA(aV, pb.v, of);
            }
            uint2 ov;
            ov.x = pk2(of[0] * inv, of[1] * inv);
            ov.y = pk2(of[2] * inv, of[3] * inv);
            *(uint2*)&L[R_A1 + (16 * qt + r16) * 64 + obc] = ov;
        }
        __syncthreads();   // S4: attention reads of K/Q/V^T done; O visible

        // ---- issue FF W1 kb0/kb1 stages into dead K region ----
        stage_sq(wsb + W1T + l * 16384, R_SKV);
        stage_sq(wsb + W1T + l * 16384 + 4096, R_SKV + 4096);

        // ---- x += O @ Wo (WoT pre-staged) ----
        #pragma unroll
        for (int kk = 0; kk < 2; ++kk) {
            const int fc = kk ? fc1 : fc0;
            short8v a = *(const short8v*)&L[R_A1 + (16 * w + r16) * 64 + fc];
            #pragma unroll
            for (int ct = 0; ct < 4; ++ct) {
                short8v bb = *(const short8v*)&L[R_WO + (16 * ct + r16) * 64 + fc];
                x[ct] = MFMA(a, bb, x[ct]);
            }
        }
        // ---- LN2(x) -> R_H2 (no barrier; own-wave stripes) ----
        #pragma unroll
        for (int j = 0; j < 4; ++j) {
            float s = x[0][j] + x[1][j] + x[2][j] + x[3][j];
            s += __shfl_xor(s, 1); s += __shfl_xor(s, 2);
            s += __shfl_xor(s, 4); s += __shfl_xor(s, 8);
            float m = s * 0.015625f;
            float q = 0.f;
            #pragma unroll
            for (int ct = 0; ct < 4; ++ct) { float d = x[ct][j] - m; q += d * d; }
            q += __shfl_xor(q, 1); q += __shfl_xor(q, 2);
            q += __shfl_xor(q, 4); q += __shfl_xor(q, 8);
            float rs = rsqrtf(q * 0.015625f + 1e-5f);
            #pragma unroll
            for (int ct = 0; ct < 4; ++ct) {
                int col = 16 * ct + r16;
                float hv = (x[ct][j] - m) * rs * lnp[128 + col] + lnp[192 + col];
                L[R_H2 + (16 * w + 4 * g + j) * 64 + (col ^ (cxw | (j << 3)))] = f2bf(hv);
            }
        }

        // ---- FF: x += relu(h2@W1+b1)@W2, double-buffered, 1 barrier per kb ----
        auto ff_step = [&](int w1b, int w2b, int kb) {
            f32x4 tacc[4] = {zf, zf, zf, zf};
            #pragma unroll
            for (int kk = 0; kk < 2; ++kk) {
                const int fc = kk ? fc1 : fc0;
                short8v a = *(const short8v*)&L[R_H2 + (16 * w + r16) * 64 + fc];
                #pragma unroll
                for (int ct = 0; ct < 4; ++ct) {
                    short8v bb = *(const short8v*)&L[w1b + (16 * ct + r16) * 64 + fc];
                    tacc[ct] = MFMA(a, bb, tacc[ct]);
                }
            }
            #pragma unroll
            for (int ct = 0; ct < 4; ++ct)
                #pragma unroll
                for (int j = 0; j < 4; ++j) {
                    float v = fmaxf(tacc[ct][j] + b1f[kb * 64 + 16 * ct + r16], 0.f);
                    L[R_A1 + (16 * w + 4 * g + j) * 64 + ((16 * ct + r16) ^ (cxw | (j << 3)))] = f2bf(v);
                }
            #pragma unroll
            for (int kk = 0; kk < 2; ++kk) {
                const int fc = kk ? fc1 : fc0;
                short8v a = *(const short8v*)&L[R_A1 + (16 * w + r16) * 64 + fc];
                #pragma unroll
                for (int ct = 0; ct < 4; ++ct) {
                    short8v bb = *(const short8v*)&L[w2b + (16 * ct + r16) * 64 + fc];
                    x[ct] = MFMA(a, bb, x[ct]);
                }
            }
        };

        __syncthreads();   // Sff0
        ff_step(R_SKV, R_W2B0, 0);
        __syncthreads();   // Sff1
        stage_sq(wsb + W1T + l * 16384 + 2 * 4096, R_SKV);
        stage_w2(2, R_W2B0);
        ff_step(R_SKV + 4096, R_W2B1, 1);
        __syncthreads();   // Sff2
        stage_sq(wsb + W1T + l * 16384 + 3 * 4096, R_SKV + 4096);
        stage_w2(3, R_W2B1);
        ff_step(R_SKV, R_W2B0, 2);
        __syncthreads();   // Sff3
        ff_step(R_SKV + 4096, R_W2B1, 3);
        #pragma unroll
        for (int ct = 0; ct < 4; ++ct)
            #pragma unroll
            for (int j = 0; j < 4; ++j) x[ct][j] += b2f[16 * ct + r16];
        __syncthreads();   // S9L
    }

    // ---------------- policy head epilogue (policy_kernel folded in) ----------------
    // stage output row x[lidx] into lnp (dead after last layer)
    if (w == (lidx >> 4) && g == ((lidx >> 2) & 3)) {
        int j = lidx & 3;
        #pragma unroll
        for (int ct = 0; ct < 4; ++ct) {
            float v = (j == 0) ? x[ct][0] : (j == 1) ? x[ct][1] : (j == 2) ? x[ct][2] : x[ct][3];
            lnp[16 * ct + r16] = v;
        }
    }
    __syncthreads();
    {   // h1 = relu(x @ Wp1 + bp1): thread = hidden unit; Wp1 reads coalesced, L2-resident
        float acc = bp1[tid];
        #pragma unroll 16
        for (int k = 0; k < 64; ++k) acc = fmaf(lnp[k], Wp1[k * 256 + tid], acc);
        b1f[tid] = fmaxf(acc, 0.f);        // reuse b1f as sh1[256]
    }
    __syncthreads();
    if (tid < 224) {
        int j = tid >> 4, gg = tid & 15;
        float a = 0.f;
        #pragma unroll
        for (int kk = 0; kk < 16; ++kk) {
            int k = gg * 16 + kk;
            a = fmaf(b1f[k], Wp2[k * 14 + j], a);
        }
        a += __shfl_xor(a, 1); a += __shfl_xor(a, 2);
        a += __shfl_xor(a, 4); a += __shfl_xor(a, 8);
        if (gg == 0) {
            float pol = a + bp2[j];
            if (j < 7) outStd[(size_t)b * 7 + j] = softplusf(pol);
            else       outMu[(size_t)b * 7 + (j - 7)] = tanhf(pol);
        }
    }
}

extern "C" void kernel_launch(void* const* d_in, const int* in_sizes, int n_in,
                              void* d_out, int out_size, void* d_ws, size_t ws_size,
                              hipStream_t stream) {
    const float* obs   = (const float*)d_in[0];
    const float* seqIn = (const float*)d_in[1];
    const float* mem   = (const float*)d_in[2];
    const int*   len   = (const int*)d_in[3];
    const float* ln_g  = (const float*)d_in[4];
    const float* ln_b  = (const float*)d_in[5];
    const float* Wemb  = (const float*)d_in[6];
    const float* ln1g  = (const float*)d_in[7];
    const float* ln1b  = (const float*)d_in[8];
    const float* ln2g  = (const float*)d_in[9];
    const float* ln2b  = (const float*)d_in[10];
    const float* Wq    = (const float*)d_in[11];
    const float* Wk    = (const float*)d_in[12];
    const float* Wv    = (const float*)d_in[13];
    const float* Wo    = (const float*)d_in[14];
    const float* W1    = (const float*)d_in[15];
    const float* b1    = (const float*)d_in[16];
    const float* W2    = (const float*)d_in[17];
    const float* b2    = (const float*)d_in[18];
    const float* Wp1   = (const float*)d_in[19];
    const float* bp1   = (const float*)d_in[20];
    const float* Wp2   = (const float*)d_in[21];
    const float* bp2   = (const float*)d_in[22];

    float* out    = (float*)d_out;
    float* outMu  = out;
    float* outStd = out + O_STD;
    float* outSeq = out + O_SEQ;
    float* outMem = out + O_MEM;
    float* outLen = out + O_LEN;
    short* wsb    = (short*)((char*)d_ws + 524288);

    hipLaunchKernelGGL(prep_weights, dim3(384), dim3(256), 0, stream,
                       Wq, Wk, Wv, Wo, W1, W2, Wemb, wsb);
    hipLaunchKernelGGL(obs_ln_kernel, dim3(512), dim3(256), 0, stream,
                       obs, ln_g, ln_b, len, outSeq, outLen);
    hipLaunchKernelGGL(mega_kernel, dim3(2048), dim3(256), 0, stream,
                       seqIn, outSeq, mem, len, ln1g, ln1b, ln2g, ln2b, b1, b2,
                       wsb, Wp1, bp1, Wp2, bp2, outMem, outMu, outStd);
}

// Round 19
// 437.681 us; speedup vs baseline: 2.3155x; 1.0084x over previous
//
#include <hip/hip_runtime.h>
#include <hip/hip_bf16.h>
#include <math.h>

// B=2048 S=64 D=6 H=4 DM=64 SS=150 A=7 HID=256 FF=256 DH=16
#define NB 2048

#define LD4(p) (*(const float4*)(p))

// out layout (floats): mu[14336] std[14336] seq[19660800] mem[50331648] len[2048]
#define O_STD 14336
#define O_SEQ 28672
#define O_MEM 19689472
#define O_LEN 70021120

// ws layout: bf16 weights at byte 524288.
#define WQT 0
#define WKT 24576
#define WVT 49152
#define WOT 73728
#define W1T 98304
#define W2T 196608
#define WET 294912

typedef __attribute__((ext_vector_type(8))) short short8v;  // 8 bf16 = 4 VGPRs
typedef __attribute__((ext_vector_type(4))) float f32x4;

#define MFMA(a, b, c) __builtin_amdgcn_mfma_f32_16x16x32_bf16((a), (b), (c), 0, 0, 0)

// 0.25 (attn scale) * log2(e): Q pre-scaled so softmax uses exp2 directly.
#define QSC 0.36067376022224087f

// LDS regions (short indices). Total L[36864] = 72KB (+fls) -> 2 blocks/CU.
#define R_SKV   0       // kv_in: mem rows 0-63 @0, h rows 64-127 @4096; -> K; -> W1 dbuf
#define R_A1    8192    // WqT -> sO -> T
#define R_VT    12288   // WkT @12288, WvT @16384 -> V^T[64][128] spans 12288..20479
#define R_WO    20480   // WoT (dedicated, staged phase 0)
#define R_H2    24576   // sQ (post QK-GEMM) -> LN2 output
#define R_W2B0  28672   // FF W2 chunk dbuf
#define R_W2B1  32768

// HW bf16 convert (RNE).
__device__ __forceinline__ short f2bf(float f) {
    return __builtin_bit_cast(short, (__bf16)f);
}
// packed pair convert: one v_cvt_pk_bf16_f32 (lo -> bits 0-15).
__device__ __forceinline__ unsigned pk2(float lo, float hi) {
    union { __hip_bfloat162 h; unsigned u; } t;
    t.h = __float22bfloat162_rn(make_float2(lo, hi));
    return t.u;
}

__device__ __forceinline__ float softplusf(float v) {
    return fmaxf(v, 0.f) + log1pf(expf(-fabsf(v)));
}

// ---------------- prep: fp32 weights -> bf16 transposed in ws ----------------
__global__ __launch_bounds__(256) void prep_weights(
        const float* __restrict__ Wq, const float* __restrict__ Wk,
        const float* __restrict__ Wv, const float* __restrict__ Wo,
        const float* __restrict__ W1, const float* __restrict__ W2,
        const float* __restrict__ Wemb, short* __restrict__ wsb) {
    int idx = blockIdx.x * 256 + threadIdx.x;          // grid covers 98304
    {
        int l = idx >> 14, r = idx & 16383;
        { int n = r >> 6, k = r & 63;
          wsb[W1T + idx] = f2bf(W1[l * 16384 + k * 256 + n]); }
        { int n = r >> 8, k = r & 255;
          wsb[W2T + idx] = f2bf(W2[l * 16384 + k * 64 + n]); }
    }
    if (idx < 24576) {                                  // 4 square mats [64n][64k]
        int l = idx >> 12, r = idx & 4095;
        int n = r >> 6, k = r & 63;
        int s = l * 4096 + k * 64 + n;
        wsb[WQT + idx] = f2bf(Wq[s]);
        wsb[WKT + idx] = f2bf(Wk[s]);
        wsb[WVT + idx] = f2bf(Wv[s]);
        wsb[WOT + idx] = f2bf(Wo[s]);
    }
    if (idx < 10240) {                                  // WembT [64n][160k]
        int n = idx / 160, k = idx - n * 160;
        wsb[WET + idx] = (k < 150) ? f2bf(Wemb[k * 64 + n]) : (short)0;
    }
}

// ---------------- MFMA mega kernel (r18 + obs-LN fold; 2-kernel pipeline) ----------------
__global__ __launch_bounds__(256, 2) void mega_kernel(
        const float* __restrict__ obs,      // raw observation (B,150)
        const float* __restrict__ lng, const float* __restrict__ lnb,  // input LN params
        const float* __restrict__ seqIn,    // original sequence (S,B,150)
        float* __restrict__ outSeq,         // seq output (fully written here)
        float* __restrict__ outLen,
        const float* __restrict__ memory,
        const int* __restrict__ len,
        const float* __restrict__ ln1g, const float* __restrict__ ln1b,
        const float* __restrict__ ln2g, const float* __restrict__ ln2b,
        const float* __restrict__ b1, const float* __restrict__ b2,
        const short* __restrict__ wsb,
        const float* __restrict__ Wp1, const float* __restrict__ bp1,
        const float* __restrict__ Wp2, const float* __restrict__ bp2,
        float* __restrict__ memOut,
        float* __restrict__ outMu, float* __restrict__ outStd) {
    __shared__ short L[36864];
    __shared__ float fls[576];
    float* lnp = fls;
    float* b1f = fls + 256;
    float* b2f = fls + 512;

    const int tid = threadIdx.x;
    const int b = blockIdx.x;
    const int w = tid >> 6;
    const int lane = tid & 63;
    const int g = lane >> 4;
    const int r16 = lane & 15;

    const int lenraw = len[b];
    const int lidx = min(max(lenraw, 0), 63);
    const bool reset = (((lenraw + 1) & 63) == 0);

    // hoisted swizzle constants
    const int cxa = (r16 & 7) << 3;            // fragment-read XOR (rows 16X+r16)
    const int fc0 = (8 * g) ^ cxa;             // col offset, kk=0
    const int fc1 = (32 + 8 * g) ^ cxa;        // col offset, kk=1
    const int cxw = (g & 1) << 5;              // D-write XOR base: cxw|(j<<3)
    const int cxm = ((tid >> 2) & 7) << 3;     // mem-stage row XOR

    const short8v zs = {0, 0, 0, 0, 0, 0, 0, 0};
    const f32x4 zf = {0.f, 0.f, 0.f, 0.f};

    // ---------------- obs LayerNorm (obs_ln kernel folded: wave 0 only) ----------------
    if (w == 0) {
        const float* row = obs + (size_t)b * 150;
        float v0 = row[lane], v1 = row[64 + lane];
        float v2 = (lane < 22) ? row[128 + lane] : 0.f;
        float s = v0 + v1 + v2;
        #pragma unroll
        for (int m = 1; m <= 32; m <<= 1) s += __shfl_xor(s, m);
        float mean = s * (1.0f / 150.0f);
        float d0 = v0 - mean, d1 = v1 - mean;
        float d2 = (lane < 22) ? (v2 - mean) : 0.f;
        float q = d0 * d0 + d1 * d1 + d2 * d2;
        #pragma unroll
        for (int m = 1; m <= 32; m <<= 1) q += __shfl_xor(q, m);
        float rs = rsqrtf(q * (1.0f / 150.0f) + 1e-5f);
        float o0 = d0 * rs * lng[lane] + lnb[lane];
        float o1 = d1 * rs * lng[64 + lane] + lnb[64 + lane];
        float* orow = outSeq + ((size_t)lidx * NB + b) * 150;
        lnp[lane] = o0;       orow[lane] = o0;
        lnp[64 + lane] = o1;  orow[64 + lane] = o1;
        if (lane < 22) {
            float o2 = d2 * rs * lng[128 + lane] + lnb[128 + lane];
            lnp[128 + lane] = o2; orow[128 + lane] = o2;
        }
        if (lane == 0) outLen[b] = (float)((lenraw + 1) & 63);
    }
    __syncthreads();   // lnp (obs LN row) visible to the wave owning row lidx

    // ---------------- embedding + inline seq copy ----------------
    #pragma unroll 1
    for (int j = 0; j < 16; ++j) {
        int r = w * 16 + j;
        int rb = r * 160;
        const size_t ro = ((size_t)r * NB + b) * 150;
        float v0, v1, v2;
        if (r == lidx) {
            v0 = lnp[lane]; v1 = lnp[64 + lane];
            v2 = (lane < 22) ? lnp[128 + lane] : 0.f;
        } else {
            const float* srow = seqIn + ro;
            v0 = srow[lane]; v1 = srow[64 + lane];
            v2 = (lane < 22) ? srow[128 + lane] : 0.f;
            float* orow = outSeq + ro;
            orow[lane]      = v0;
            orow[64 + lane] = v1;
            if (lane < 22) orow[128 + lane] = v2;
        }
        L[rb + lane]      = f2bf(v0);
        L[rb + 64 + lane] = f2bf(v1);
        if (lane < 32) L[rb + 128 + lane] = (lane < 22) ? f2bf(v2) : (short)0;
    }
    {
        const int4* s4p = (const int4*)(wsb + WET);
        int4* d4p = (int4*)(L + 10240);
        #pragma unroll
        for (int i = 0; i < 5; ++i) d4p[tid + i * 256] = s4p[tid + i * 256];
    }
    __syncthreads();

    f32x4 x[4] = {zf, zf, zf, zf};
    #pragma unroll
    for (int kk = 0; kk < 5; ++kk) {
        short8v a = *(const short8v*)&L[(16 * w + r16) * 160 + kk * 32 + 8 * g];
        #pragma unroll
        for (int ct = 0; ct < 4; ++ct) {
            short8v bb = *(const short8v*)&L[10240 + (16 * ct + r16) * 160 + kk * 32 + 8 * g];
            x[ct] = MFMA(a, bb, x[ct]);
        }
    }
    __syncthreads();

    // ---------------- 6 transformer layers (r17-proven body) ----------------
    #pragma unroll 1
    for (int l = 0; l < 6; ++l) {
        auto stage_sq = [&](const short* src, int dstbase) {
            const int4* s = (const int4*)src;
            int4* d = (int4*)(L + dstbase);
            #pragma unroll
            for (int i = 0; i < 2; ++i) {
                int idx = tid + i * 256;
                d[idx ^ ((idx >> 3) & 7)] = s[idx];
            }
        };
        auto stage_w2 = [&](int kb, int dstbase) {
            int4* d = (int4*)(L + dstbase);
            #pragma unroll
            for (int i = 0; i < 2; ++i) {
                int idx = tid + i * 256;
                int sx = idx ^ ((idx >> 3) & 7);
                int n = idx >> 3, c = idx & 7;
                d[sx] = *(const int4*)&wsb[W2T + l * 16384 + n * 256 + kb * 64 + c * 8];
            }
        };

        // ---- phase 0: stage everything for this layer ----
        if (tid < 64) {
            lnp[tid]       = ln1g[l * 64 + tid];
            lnp[64 + tid]  = ln1b[l * 64 + tid];
            lnp[128 + tid] = ln2g[l * 64 + tid];
            lnp[192 + tid] = ln2b[l * 64 + tid];
            b2f[tid]       = b2[l * 64 + tid];
        }
        b1f[tid] = b1[l * 256 + tid];
        {   // mem -> sKV rows 0..63 (bf16, swizzled) + memOut passthrough
            const float* gmem = memory + ((size_t)l * NB + b) * 4096;
            float* gout = memOut + ((size_t)l * NB + b) * 4096;
            int rr = tid >> 2, c0 = (tid & 3) * 16;
            #pragma unroll
            for (int k4 = 0; k4 < 4; ++k4) {
                float4 v = LD4(&gmem[rr * 64 + c0 + k4 * 4]);
                if (!reset) *(float4*)&gout[rr * 64 + c0 + k4 * 4] = v;
                uint2 su;
                su.x = pk2(v.x, v.y); su.y = pk2(v.z, v.w);
                *(uint2*)&L[rr * 64 + ((c0 + k4 * 4) ^ cxm)] = su;
            }
            if (reset) {
                #pragma unroll
                for (int ct = 0; ct < 4; ++ct)
                    #pragma unroll
                    for (int j = 0; j < 4; ++j)
                        gout[(16 * w + 4 * g + j) * 64 + 16 * ct + r16] = x[ct][j];
            }
        }
        stage_sq(wsb + WQT + l * 4096, R_A1);
        stage_sq(wsb + WKT + l * 4096, R_VT);
        stage_sq(wsb + WVT + l * 4096, R_VT + 4096);
        stage_sq(wsb + WOT + l * 4096, R_WO);
        stage_w2(0, R_W2B0);
        stage_w2(1, R_W2B1);
        __syncthreads();   // S1a

        // ---- LN1(x) -> sKV rows 64..127 (no barrier; own-wave stripes) ----
        #pragma unroll
        for (int j = 0; j < 4; ++j) {
            float s = x[0][j] + x[1][j] + x[2][j] + x[3][j];
            s += __shfl_xor(s, 1); s += __shfl_xor(s, 2);
            s += __shfl_xor(s, 4); s += __shfl_xor(s, 8);
            float m = s * 0.015625f;
            float q = 0.f;
            #pragma unroll
            for (int ct = 0; ct < 4; ++ct) { float d = x[ct][j] - m; q += d * d; }
            q += __shfl_xor(q, 1); q += __shfl_xor(q, 2);
            q += __shfl_xor(q, 4); q += __shfl_xor(q, 8);
            float rs = rsqrtf(q * 0.015625f + 1e-5f);
            #pragma unroll
            for (int ct = 0; ct < 4; ++ct) {
                int col = 16 * ct + r16;
                float hv = (x[ct][j] - m) * rs * lnp[col] + lnp[64 + col];
                L[(64 + 16 * w + 4 * g + j) * 64 + (col ^ (cxw | (j << 3)))] = f2bf(hv);
            }
        }

        // ---- Q + K GEMMs (pass 1) ----
        f32x4 qa[4] = {zf, zf, zf, zf};
        f32x4 ka[2][4] = {{zf, zf, zf, zf}, {zf, zf, zf, zf}};
        #pragma unroll
        for (int kk = 0; kk < 2; ++kk) {
            const int fc = kk ? fc1 : fc0;
            short8v ah = *(const short8v*)&L[(64 + 16 * w + r16) * 64 + fc];
            short8v a0 = *(const short8v*)&L[(16 * w + r16) * 64 + fc];
            #pragma unroll
            for (int ct = 0; ct < 4; ++ct) {
                short8v bq = *(const short8v*)&L[R_A1 + (16 * ct + r16) * 64 + fc];
                short8v bk = *(const short8v*)&L[R_VT + (16 * ct + r16) * 64 + fc];
                qa[ct]    = MFMA(ah, bq, qa[ct]);
                ka[0][ct] = MFMA(a0, bk, ka[0][ct]);
                ka[1][ct] = MFMA(ah, bk, ka[1][ct]);
            }
        }
        // pack Q -> R_H2 (dead region) — no barrier; visibility via S2b+S3.
        #pragma unroll
        for (int ct = 0; ct < 4; ++ct)
            #pragma unroll
            for (int j = 0; j < 4; ++j)
                L[R_H2 + (16 * w + 4 * g + j) * 64 + ((16 * ct + r16) ^ (cxw | (j << 3)))] =
                    f2bf(qa[ct][j] * QSC);

        // ---- V GEMM (pass 2) ----
        f32x4 va[2][4] = {{zf, zf, zf, zf}, {zf, zf, zf, zf}};
        #pragma unroll
        for (int kk = 0; kk < 2; ++kk) {
            const int fc = kk ? fc1 : fc0;
            short8v ah = *(const short8v*)&L[(64 + 16 * w + r16) * 64 + fc];
            short8v a0 = *(const short8v*)&L[(16 * w + r16) * 64 + fc];
            #pragma unroll
            for (int ct = 0; ct < 4; ++ct) {
                short8v bv = *(const short8v*)&L[R_VT + 4096 + (16 * ct + r16) * 64 + fc];
                va[0][ct] = MFMA(a0, bv, va[0][ct]);
                va[1][ct] = MFMA(ah, bv, va[1][ct]);
            }
        }
        __syncthreads();   // S2b: sKV A-reads + WkT/WvT B-reads done

        // pack K -> R_SKV and V -> R_VT as permuted V^T (vector b64)
        #pragma unroll
        for (int ct = 0; ct < 4; ++ct) {
            #pragma unroll
            for (int j = 0; j < 4; ++j) {
                int key0 = 16 * w + 4 * g + j;
                int colw = (16 * ct + r16) ^ (cxw | (j << 3));
                L[key0 * 64 + colw] = f2bf(ka[0][ct][j]);
                L[(64 + key0) * 64 + colw] = f2bf(ka[1][ct][j]);
            }
        }
        {
            const int p0 = ((w >> 1) << 5) | (g << 3) | ((w & 1) << 2);  // perm(key0)
            const int p1 = p0 | 64;                                       // perm(key0+64)
            #pragma unroll
            for (int ct = 0; ct < 4; ++ct) {
                int rowb = R_VT + (16 * ct + r16) * 128;
                uint2 v0, v1;
                v0.x = pk2(va[0][ct][0], va[0][ct][1]);
                v0.y = pk2(va[0][ct][2], va[0][ct][3]);
                v1.x = pk2(va[1][ct][0], va[1][ct][1]);
                v1.y = pk2(va[1][ct][2], va[1][ct][3]);
                *(uint2*)&L[rowb + (p0 ^ cxa)] = v0;
                *(uint2*)&L[rowb + (p1 ^ cxa)] = v1;
            }
        }
        __syncthreads();   // S3

        // ---- attention: wave w = head; causal-skipped blocks, no-max exp2 softmax ----
        const int hc = 16 * w;
        const int attc = (hc + 8 * g) ^ cxa;       // bQ/aK col
        const int obc  = (hc + 4 * g) ^ cxa;       // O write col base
        #pragma unroll
        for (int qt = 0; qt < 4; ++qt) {
            const int KT = 5 + qt;                 // live key blocks (kt < KT)
            short8v bQ = (g < 2) ? *(const short8v*)&L[R_H2 + (16 * qt + r16) * 64 + attc] : zs;
            f32x4 s[8];
            #pragma unroll
            for (int kt = 0; kt < 8; ++kt) if (kt < KT) {
                short8v aK = *(const short8v*)&L[(16 * kt + r16) * 64 + attc];
                s[kt] = MFMA(aK, bQ, zf);
            }
            float sum = 0.f;
            #pragma unroll
            for (int kt = 0; kt < 8; ++kt) if (kt < KT) {
                #pragma unroll
                for (int j = 0; j < 4; ++j) {
                    float e = exp2f(s[kt][j]);     // Q pre-scaled; bounded, no max needed
                    if (kt == KT - 1) e = ((4 * g + j) > r16) ? 0.f : e;  // causal edge
                    s[kt][j] = e; sum += e;
                }
            }
            sum += __shfl_xor(sum, 16);
            sum += __shfl_xor(sum, 32);
            float inv = 1.0f / sum;
            f32x4 of = zf;
            const int KT2 = (KT + 1) >> 1;
            #pragma unroll
            for (int kt2 = 0; kt2 < 4; ++kt2) if (kt2 < KT2) {
                short8v aV = *(const short8v*)&L[R_VT + (hc + r16) * 128 +
                                                 ((32 * kt2 + 8 * g) ^ cxa)];
                union { short8v v; unsigned u[4]; } pb;
                const int i0 = 2 * kt2, i1 = 2 * kt2 + 1;
                pb.u[0] = pk2(s[i0][0], s[i0][1]);
                pb.u[1] = pk2(s[i0][2], s[i0][3]);
                pb.u[2] = (i1 < KT) ? pk2(s[i1][0], s[i1][1]) : 0u;
                pb.u[3] = (i1 < KT) ? pk2(s[i1][2], s[i1][3]) : 0u;
                of = MFMA(aV, pb.v, of);
            }
            uint2 ov;
            ov.x = pk2(of[0] * inv, of[1] * inv);
            ov.y = pk2(of[2] * inv, of[3] * inv);
            *(uint2*)&L[R_A1 + (16 * qt + r16) * 64 + obc] = ov;
        }
        __syncthreads();   // S4: attention reads of K/Q/V^T done; O visible

        // ---- issue FF W1 kb0/kb1 stages into dead K region ----
        stage_sq(wsb + W1T + l * 16384, R_SKV);
        stage_sq(wsb + W1T + l * 16384 + 4096, R_SKV + 4096);

        // ---- x += O @ Wo (WoT pre-staged) ----
        #pragma unroll
        for (int kk = 0; kk < 2; ++kk) {
            const int fc = kk ? fc1 : fc0;
            short8v a = *(const short8v*)&L[R_A1 + (16 * w + r16) * 64 + fc];
            #pragma unroll
            for (int ct = 0; ct < 4; ++ct) {
                short8v bb = *(const short8v*)&L[R_WO + (16 * ct + r16) * 64 + fc];
                x[ct] = MFMA(a, bb, x[ct]);
            }
        }
        // ---- LN2(x) -> R_H2 (no barrier; own-wave stripes) ----
        #pragma unroll
        for (int j = 0; j < 4; ++j) {
            float s = x[0][j] + x[1][j] + x[2][j] + x[3][j];
            s += __shfl_xor(s, 1); s += __shfl_xor(s, 2);
            s += __shfl_xor(s, 4); s += __shfl_xor(s, 8);
            float m = s * 0.015625f;
            float q = 0.f;
            #pragma unroll
            for (int ct = 0; ct < 4; ++ct) { float d = x[ct][j] - m; q += d * d; }
            q += __shfl_xor(q, 1); q += __shfl_xor(q, 2);
            q += __shfl_xor(q, 4); q += __shfl_xor(q, 8);
            float rs = rsqrtf(q * 0.015625f + 1e-5f);
            #pragma unroll
            for (int ct = 0; ct < 4; ++ct) {
                int col = 16 * ct + r16;
                float hv = (x[ct][j] - m) * rs * lnp[128 + col] + lnp[192 + col];
                L[R_H2 + (16 * w + 4 * g + j) * 64 + (col ^ (cxw | (j << 3)))] = f2bf(hv);
            }
        }

        // ---- FF: x += relu(h2@W1+b1)@W2, double-buffered, 1 barrier per kb ----
        auto ff_step = [&](int w1b, int w2b, int kb) {
            f32x4 tacc[4] = {zf, zf, zf, zf};
            #pragma unroll
            for (int kk = 0; kk < 2; ++kk) {
                const int fc = kk ? fc1 : fc0;
                short8v a = *(const short8v*)&L[R_H2 + (16 * w + r16) * 64 + fc];
                #pragma unroll
                for (int ct = 0; ct < 4; ++ct) {
                    short8v bb = *(const short8v*)&L[w1b + (16 * ct + r16) * 64 + fc];
                    tacc[ct] = MFMA(a, bb, tacc[ct]);
                }
            }
            #pragma unroll
            for (int ct = 0; ct < 4; ++ct)
                #pragma unroll
                for (int j = 0; j < 4; ++j) {
                    float v = fmaxf(tacc[ct][j] + b1f[kb * 64 + 16 * ct + r16], 0.f);
                    L[R_A1 + (16 * w + 4 * g + j) * 64 + ((16 * ct + r16) ^ (cxw | (j << 3)))] = f2bf(v);
                }
            #pragma unroll
            for (int kk = 0; kk < 2; ++kk) {
                const int fc = kk ? fc1 : fc0;
                short8v a = *(const short8v*)&L[R_A1 + (16 * w + r16) * 64 + fc];
                #pragma unroll
                for (int ct = 0; ct < 4; ++ct) {
                    short8v bb = *(const short8v*)&L[w2b + (16 * ct + r16) * 64 + fc];
                    x[ct] = MFMA(a, bb, x[ct]);
                }
            }
        };

        __syncthreads();   // Sff0
        ff_step(R_SKV, R_W2B0, 0);
        __syncthreads();   // Sff1
        stage_sq(wsb + W1T + l * 16384 + 2 * 4096, R_SKV);
        stage_w2(2, R_W2B0);
        ff_step(R_SKV + 4096, R_W2B1, 1);
        __syncthreads();   // Sff2
        stage_sq(wsb + W1T + l * 16384 + 3 * 4096, R_SKV + 4096);
        stage_w2(3, R_W2B1);
        ff_step(R_SKV, R_W2B0, 2);
        __syncthreads();   // Sff3
        ff_step(R_SKV + 4096, R_W2B1, 3);
        #pragma unroll
        for (int ct = 0; ct < 4; ++ct)
            #pragma unroll
            for (int j = 0; j < 4; ++j) x[ct][j] += b2f[16 * ct + r16];
        __syncthreads();   // S9L
    }

    // ---------------- policy head epilogue ----------------
    if (w == (lidx >> 4) && g == ((lidx >> 2) & 3)) {
        int j = lidx & 3;
        #pragma unroll
        for (int ct = 0; ct < 4; ++ct) {
            float v = (j == 0) ? x[ct][0] : (j == 1) ? x[ct][1] : (j == 2) ? x[ct][2] : x[ct][3];
            lnp[16 * ct + r16] = v;
        }
    }
    __syncthreads();
    {   // h1 = relu(x @ Wp1 + bp1)
        float acc = bp1[tid];
        #pragma unroll 16
        for (int k = 0; k < 64; ++k) acc = fmaf(lnp[k], Wp1[k * 256 + tid], acc);
        b1f[tid] = fmaxf(acc, 0.f);
    }
    __syncthreads();
    if (tid < 224) {
        int j = tid >> 4, gg = tid & 15;
        float a = 0.f;
        #pragma unroll
        for (int kk = 0; kk < 16; ++kk) {
            int k = gg * 16 + kk;
            a = fmaf(b1f[k], Wp2[k * 14 + j], a);
        }
        a += __shfl_xor(a, 1); a += __shfl_xor(a, 2);
        a += __shfl_xor(a, 4); a += __shfl_xor(a, 8);
        if (gg == 0) {
            float pol = a + bp2[j];
            if (j < 7) outStd[(size_t)b * 7 + j] = softplusf(pol);
            else       outMu[(size_t)b * 7 + (j - 7)] = tanhf(pol);
        }
    }
}

extern "C" void kernel_launch(void* const* d_in, const int* in_sizes, int n_in,
                              void* d_out, int out_size, void* d_ws, size_t ws_size,
                              hipStream_t stream) {
    const float* obs   = (const float*)d_in[0];
    const float* seqIn = (const float*)d_in[1];
    const float* mem   = (const float*)d_in[2];
    const int*   len   = (const int*)d_in[3];
    const float* ln_g  = (const float*)d_in[4];
    const float* ln_b  = (const float*)d_in[5];
    const float* Wemb  = (const float*)d_in[6];
    const float* ln1g  = (const float*)d_in[7];
    const float* ln1b  = (const float*)d_in[8];
    const float* ln2g  = (const float*)d_in[9];
    const float* ln2b  = (const float*)d_in[10];
    const float* Wq    = (const float*)d_in[11];
    const float* Wk    = (const float*)d_in[12];
    const float* Wv    = (const float*)d_in[13];
    const float* Wo    = (const float*)d_in[14];
    const float* W1    = (const float*)d_in[15];
    const float* b1    = (const float*)d_in[16];
    const float* W2    = (const float*)d_in[17];
    const float* b2    = (const float*)d_in[18];
    const float* Wp1   = (const float*)d_in[19];
    const float* bp1   = (const float*)d_in[20];
    const float* Wp2   = (const float*)d_in[21];
    const float* bp2   = (const float*)d_in[22];

    float* out    = (float*)d_out;
    float* outMu  = out;
    float* outStd = out + O_STD;
    float* outSeq = out + O_SEQ;
    float* outMem = out + O_MEM;
    float* outLen = out + O_LEN;
    short* wsb    = (short*)((char*)d_ws + 524288);

    hipLaunchKernelGGL(prep_weights, dim3(384), dim3(256), 0, stream,
                       Wq, Wk, Wv, Wo, W1, W2, Wemb, wsb);
    hipLaunchKernelGGL(mega_kernel, dim3(2048), dim3(256), 0, stream,
                       obs, ln_g, ln_b, seqIn, outSeq, outLen,
                       mem, len, ln1g, ln1b, ln2g, ln2b, b1, b2,
                       wsb, Wp1, bp1, Wp2, bp2, outMem, outMu, outStd);
}